// Round 14
// baseline (411.855 us; speedup 1.0000x reference)
//
#include <hip/hip_runtime.h>
#include <math.h>

typedef _Float16 half8 __attribute__((ext_vector_type(8)));
typedef _Float16 h2 __attribute__((ext_vector_type(2)));
typedef float f32x4 __attribute__((ext_vector_type(4)));
typedef unsigned int u32x4 __attribute__((ext_vector_type(4)));
typedef unsigned int u32x2 __attribute__((ext_vector_type(2)));

namespace {
constexpr int kNS = 16;
constexpr int kNV = 4;
constexpr int kNG = 50;
constexpr int kHID = 64;
constexpr int kAttr = 28;                 // NS + 3*NV
constexpr int kWNUM = 400;
constexpr float kStep = 5.0f / 49.0f;
constexpr float kCoeff = -0.5f / (kStep * kStep);
constexpr float kSqrt3 = 1.7320508075688772f;
constexpr float kInvSqrt3 = 0.57735026918962576f;
constexpr float kInvSqrt20 = 0.22360679774997896f;
// Row = 208 B (13 granules): 52 words == 20 mod 32 -> 16 rows spread over 8
// bank-offset classes (2 lanes/bank = free). No XOR swizzle (r3 lesson).
constexpr int kRowB = 208;
constexpr int kImg1Bytes = 96 * 64 * 2;   // 12288
constexpr int kImg2Bytes = 64 * 400 * 2;  // 51200
}  // namespace

// f16 end-to-end (r6-r13: absmax 0.016-0.09 vs threshold 0.101).
// (_Float16) cast = hardware v_cvt_f16_f32 RNE (r5: hip bf16 helpers truncate).
__device__ __forceinline__ unsigned short f2h(float x) {
  _Float16 h = (_Float16)x;
  unsigned short r;
  __builtin_memcpy(&r, &h, 2);
  return r;
}
__device__ __forceinline__ unsigned pack2(float lo, float hi) {
  return (unsigned)f2h(lo) | ((unsigned)f2h(hi) << 16);
}

// ---------- A: fused init (agg = node_attr; cnt = 0; f16 weight images) ------
__global__ __launch_bounds__(256) void init_kernel(
    const float* __restrict__ W1, const float* __restrict__ W2,
    const float* __restrict__ node_attr,
    unsigned short* __restrict__ img1, unsigned short* __restrict__ img2,
    int* __restrict__ cnt, float* __restrict__ agg, int aggN4, int N) {
  const int gtid = blockIdx.x * 256 + threadIdx.x;
  const int gsz = gridDim.x * 256;
  f32x4* agg4 = (f32x4*)agg;
  const f32x4* na4 = (const f32x4*)node_attr;
  for (int i = gtid; i < aggN4; i += gsz) agg4[i] = na4[i];
  for (int i = gtid; i < N; i += gsz) cnt[i] = 0;
  // img layout: element (k, n) at byte ((k>>3)*W + n)*16 + 2*(k&7)
  for (int i = gtid; i < 96 * 64 + 64 * 400; i += gsz) {
    if (i < 96 * 64) {
      const int m = i >> 6, n = i & 63;
      float v = 0.0f;
      if (m < 50) v = W1[m * 64 + n];                        // gaussian rows
      else if (m >= 56 && m < 88) v = W1[(m - 6) * 64 + n];  // ss, ds rows
      img1[((m >> 3) * 64 + n) * 8 + (m & 7)] = f2h(v);
    } else {
      const int j = i - 96 * 64;
      const int m = j / 400, n = j % 400;
      img2[((m >> 3) * 400 + n) * 8 + (m & 7)] = f2h(W2[m * 400 + n]);
    }
  }
}

// ---------- B: histogram of dst + per-edge rank (the ONLY atomic pass) -------
__global__ __launch_bounds__(256) void hist_rank_kernel(
    const int* __restrict__ edge_index, int* __restrict__ cnt,
    int* __restrict__ rank, int E) {
  const int e = blockIdx.x * blockDim.x + threadIdx.x;
  if (e >= E) return;
  rank[e] = atomicAdd(cnt + edge_index[E + e], 1);
}

// ---------- C: exclusive scan cnt -> node_start (single block, wave-scan) ----
__global__ __launch_bounds__(256) void scan_kernel(
    const int* __restrict__ cnt, int* __restrict__ node_start, int N) {
  __shared__ int wsum[4];
  const int tid = threadIdx.x;
  const int lane = tid & 63;
  const int wv = tid >> 6;
  const int n4 = (N + 3) >> 2;
  const int tiles = (n4 + 255) / 256;
  int running = 0;
  for (int k = 0; k < tiles; ++k) {
    const int i4 = k * 256 + tid;
    int4 v = {0, 0, 0, 0};
    const int base = i4 * 4;
    if (i4 < n4) {
      if (base + 3 < N) {
        v = *(const int4*)(cnt + base);
      } else {
        if (base + 0 < N) v.x = cnt[base + 0];
        if (base + 1 < N) v.y = cnt[base + 1];
        if (base + 2 < N) v.z = cnt[base + 2];
      }
    }
    const int e1 = v.x, e2 = v.x + v.y, e3 = e2 + v.z, s4 = e3 + v.w;
    int incl = s4;
#pragma unroll
    for (int d = 1; d < 64; d <<= 1) {
      const int y = __shfl_up(incl, d);
      if (lane >= d) incl += y;
    }
    if (lane == 63) wsum[wv] = incl;
    __syncthreads();
    int wbase = 0;
#pragma unroll
    for (int w = 0; w < 4; ++w) wbase += (w < wv) ? wsum[w] : 0;
    const int block_total = wsum[0] + wsum[1] + wsum[2] + wsum[3];
    const int tbase = running + wbase + (incl - s4);
    if (i4 < n4) {
      if (base + 0 < N) node_start[base + 0] = tbase;
      if (base + 1 < N) node_start[base + 1] = tbase + e1;
      if (base + 2 < N) node_start[base + 2] = tbase + e2;
      if (base + 3 < N) node_start[base + 3] = tbase + e3;
    }
    running += block_total;
    __syncthreads();  // wsum reused next tile
  }
}

// ---------- D: scatter (ATOMIC-FREE: slot = node_start[d] + rank[e]) ---------
__global__ __launch_bounds__(256) void scatter_kernel(
    const int* __restrict__ edge_index, const int* __restrict__ node_start,
    const int* __restrict__ rank, int2* __restrict__ sedge, int E) {
  const int e = blockIdx.x * blockDim.x + threadIdx.x;
  if (e >= E) return;
  const int s = edge_index[e];
  const int d = edge_index[E + e];
  sedge[node_start[d] + rank[e]] = int2{s, d};
}

// ---------- E: main MFMA edge kernel ----------
// r14 instruction diet (r13 analysis: LDS unit is the busiest engine; ~350
// ds-ops/wave incl. 174 shfl-bpermutes + 100 scalar o0 reads):
//  - o0 broadcast reads batched as ds_read_b128 (100 -> 36 ops)
//  - sh/v1 stash repacked to 16B-aligned chunks 8..12 -> b128 hoist (24 -> 8)
//  - segmented shuffle reduce in packed f16 (v_pk_add_f16): 174 -> 90
//    bpermutes; errors enter the segment SUM then get /cnt (mean) -> small.
// ub row (208B) timeline: ef(96 f16, chunks 0..11) -> h(chunks 0..7) +
// sh/v1 stash(chunks 8..12) -> o0 f32(chunks 0..4, after hf hoist) ->
// msg(28 f32, chunks 0..6). LDS 53248 B => 3 blocks/CU. All LDS wave-local.
__global__ __launch_bounds__(256, 3) void tfn_mfma_kernel(
    const float* __restrict__ node_attr, const float* __restrict__ pos,
    const float* __restrict__ b1, const float* __restrict__ b2,
    const char* __restrict__ img1, const char* __restrict__ img2,
    const int2* __restrict__ sedge, const int* __restrict__ cnt,
    float* __restrict__ agg, int E) {
  __shared__ __align__(16) char ub[256 * kRowB];   // 53248 B (3 blocks/CU)

  const int tid = threadIdx.x;
  const int t = blockIdx.x * 256 + tid;
  const int lane = tid & 63;
  const int wv = tid >> 6;
  const int lc = lane & 15, lq = lane >> 4;

  const bool valid = (t < E);
  int src = 0, dstv = -1;
  if (valid) {
    const int2 se = sedge[t];
    src = se.x;
    dstv = se.y;
  }
  const int dn = valid ? dstv : 0;

  // ---- geometry ----
  const float psx = pos[src * 3 + 0], psy = pos[src * 3 + 1], psz = pos[src * 3 + 2];
  const float pdx = pos[dn * 3 + 0], pdy = pos[dn * 3 + 1], pdz = pos[dn * 3 + 2];
  const float vx = pdx - psx, vy = pdy - psy, vz = pdz - psz;
  const float dist = sqrtf(vx * vx + vy * vy + vz * vz);
  const float rinv = 1.0f / fmaxf(dist, 1e-8f);
  const float sh0 = kSqrt3 * (vy * rinv);
  const float sh1 = kSqrt3 * (vz * rinv);
  const float sh2 = kSqrt3 * (vx * rinv);

  const float* nas = node_attr + (size_t)src * kAttr;
  const float* nad = node_attr + (size_t)dn * kAttr;
  const float4 sa = *(const float4*)(nas + 0);
  const float4 sb = *(const float4*)(nas + 4);
  const float4 sc4 = *(const float4*)(nas + 8);
  const float4 sd4 = *(const float4*)(nas + 12);
  const float4 va = *(const float4*)(nas + 16);
  const float4 vb = *(const float4*)(nas + 20);
  const float4 vc = *(const float4*)(nas + 24);
  const float4 da = *(const float4*)(nad + 0);
  const float4 db = *(const float4*)(nad + 4);
  const float4 dc4 = *(const float4*)(nad + 8);
  const float4 dd4 = *(const float4*)(nad + 12);

  char* myrow = ub + tid * kRowB;

  // ---- write ef row (96 f16): [gauss50 | 0x6 | ss16 | ds16 | 0x8] ----
  {
    const float base = dist + 1e-6f;
#pragma unroll
    for (int c = 0; c < 6; ++c) {
      unsigned p[4];
#pragma unroll
      for (int u = 0; u < 4; ++u) {
        const int k = c * 8 + u * 2;
        const float d0 = base - (float)k * kStep;
        const float d1 = base - (float)(k + 1) * kStep;
        p[u] = pack2(__expf(kCoeff * d0 * d0), __expf(kCoeff * d1 * d1));
      }
      *(u32x4*)(myrow + c * 16) = u32x4{p[0], p[1], p[2], p[3]};
    }
    const float d0 = base - 48.0f * kStep, d1 = base - 49.0f * kStep;
    *(u32x4*)(myrow + 6 * 16) =
        u32x4{pack2(__expf(kCoeff * d0 * d0), __expf(kCoeff * d1 * d1)), 0u, 0u, 0u};
    *(u32x4*)(myrow + 7 * 16) =
        u32x4{pack2(sa.x, sa.y), pack2(sa.z, sa.w), pack2(sb.x, sb.y), pack2(sb.z, sb.w)};
    *(u32x4*)(myrow + 8 * 16) =
        u32x4{pack2(sc4.x, sc4.y), pack2(sc4.z, sc4.w), pack2(sd4.x, sd4.y), pack2(sd4.z, sd4.w)};
    *(u32x4*)(myrow + 9 * 16) =
        u32x4{pack2(da.x, da.y), pack2(da.z, da.w), pack2(db.x, db.y), pack2(db.z, db.w)};
    *(u32x4*)(myrow + 10 * 16) =
        u32x4{pack2(dc4.x, dc4.y), pack2(dc4.z, dc4.w), pack2(dd4.x, dd4.y), pack2(dd4.z, dd4.w)};
    *(u32x4*)(myrow + 11 * 16) = u32x4{0u, 0u, 0u, 0u};
  }

  const float v1f[12] = {va.x, va.y, va.z, va.w, vb.x, vb.y, vb.z, vb.w,
                         vc.x, vc.y, vc.z, vc.w};

  // ---- hoist ef fragments (B-operand: lane holds ef[e=g*16+lc][k=(ks*4+lq)*8+j]) ----
  half8 eff[4][3];
#pragma unroll
  for (int g = 0; g < 4; ++g) {
    const char* rp = ub + (wv * 64 + g * 16 + lc) * kRowB;
#pragma unroll
    for (int ks = 0; ks < 3; ++ks)
      eff[g][ks] = *(const half8*)(rp + (ks * 4 + lq) * 16);
  }

  // ---- stash sh/v1 as f32, 16B-aligned per triple (chunks 8..12) ----
  *(f32x4*)(myrow + 8 * 16) = f32x4{sh0, sh1, sh2, 0.0f};
  *(f32x4*)(myrow + 9 * 16) = f32x4{v1f[0], v1f[1], v1f[2], 0.0f};
  *(f32x4*)(myrow + 10 * 16) = f32x4{v1f[3], v1f[4], v1f[5], 0.0f};
  *(f32x4*)(myrow + 11 * 16) = f32x4{v1f[6], v1f[7], v1f[8], 0.0f};
  *(f32x4*)(myrow + 12 * 16) = f32x4{v1f[9], v1f[10], v1f[11], 0.0f};

  // ---- MFMA-1: h[n][e] = relu(b1[n] + sum_k W1p[k][n] ef[e][k]) ----
#pragma unroll
  for (int nt = 0; nt < 4; ++nt) {
    const half8 a0 = *(const half8*)(img1 + ((0 + lq) * 64 + nt * 16 + lc) * 16);
    const half8 a1 = *(const half8*)(img1 + ((4 + lq) * 64 + nt * 16 + lc) * 16);
    const half8 a2 = *(const half8*)(img1 + ((8 + lq) * 64 + nt * 16 + lc) * 16);
    const f32x4 bias = *(const f32x4*)(b1 + nt * 16 + lq * 4);
#pragma unroll
    for (int g = 0; g < 4; ++g) {
      f32x4 acc = bias;
      acc = __builtin_amdgcn_mfma_f32_16x16x32_f16(a0, eff[g][0], acc, 0, 0, 0);
      acc = __builtin_amdgcn_mfma_f32_16x16x32_f16(a1, eff[g][1], acc, 0, 0, 0);
      acc = __builtin_amdgcn_mfma_f32_16x16x32_f16(a2, eff[g][2], acc, 0, 0, 0);
      const unsigned p0 = pack2(fmaxf(acc[0], 0.0f), fmaxf(acc[1], 0.0f));
      const unsigned p1 = pack2(fmaxf(acc[2], 0.0f), fmaxf(acc[3], 0.0f));
      const int row = wv * 64 + g * 16 + lc;
      // n = nt*16 + lq*4 + r -> byte 2n = nt*32 + lq*8
      *(u32x2*)(ub + row * kRowB + nt * 32 + lq * 8) = u32x2{p0, p1};
    }
  }

  // ---- load h fragments (B-operand: lane holds h[k][e=g*16+lc]) ----
  half8 hf[4][2];
#pragma unroll
  for (int g = 0; g < 4; ++g) {
    const char* rp = ub + (wv * 64 + g * 16 + lc) * kRowB;
    hf[g][0] = *(const half8*)(rp + (0 + lq) * 16);
    hf[g][1] = *(const half8*)(rp + (4 + lq) * 16);
  }

  // ---- hoist per-edge sh / v1 via b128 (8 reads; was 24 scalar) ----
  float shv[4][3], v1h[4][3];
#pragma unroll
  for (int g = 0; g < 4; ++g) {
    const char* rp = ub + (wv * 64 + g * 16 + lc) * kRowB;
    const f32x4 s4 = *(const f32x4*)(rp + 128);
    shv[g][0] = s4[0]; shv[g][1] = s4[1]; shv[g][2] = s4[2];
    const f32x4 v4 = *(const f32x4*)(rp + 144 + 16 * lq);
    v1h[g][0] = v4[0]; v1h[g][1] = v4[1]; v1h[g][2] = v4[2];
  }

  // ---- o0[20] as f32 into chunks 0..4 (h region dead now that hf is in regs) ----
  {
    const float t0 = (v1f[0] * sh0 + v1f[1] * sh1 + v1f[2] * sh2) * kInvSqrt3;
    const float t1 = (v1f[3] * sh0 + v1f[4] * sh1 + v1f[5] * sh2) * kInvSqrt3;
    const float t2 = (v1f[6] * sh0 + v1f[7] * sh1 + v1f[8] * sh2) * kInvSqrt3;
    const float t3 = (v1f[9] * sh0 + v1f[10] * sh1 + v1f[11] * sh2) * kInvSqrt3;
    *(f32x4*)(myrow + 0) = f32x4{sa.x, sa.y, sa.z, sa.w};
    *(f32x4*)(myrow + 16) = f32x4{sb.x, sb.y, sb.z, sb.w};
    *(f32x4*)(myrow + 32) = f32x4{sc4.x, sc4.y, sc4.z, sc4.w};
    *(f32x4*)(myrow + 48) = f32x4{sd4.x, sd4.y, sd4.z, sd4.w};
    *(f32x4*)(myrow + 64) = f32x4{t0, t1, t2, t3};
  }

  // ---- MFMA-2 + fused contraction. D[n][e]: lane owns edge lc, n = 16nt+4lq+r ----
  float macc0[4][4] = {};
  float macc1[4][4][3] = {};

  // nt = 0..19 restructured q-outer: one b128 o0 load per (q,g), compile-time
  // element extracts in the unrolled r loop.
#pragma unroll
  for (int q = 0; q < 5; ++q) {
    f32x4 o0q[4];
#pragma unroll
    for (int g = 0; g < 4; ++g)
      o0q[g] = *(const f32x4*)(ub + (wv * 64 + g * 16 + lc) * kRowB + 16 * q);
#pragma unroll
    for (int r = 0; r < 4; ++r) {
      const int nt = q * 4 + r;
      const half8 w0 = *(const half8*)(img2 + ((0 + lq) * 400 + nt * 16 + lc) * 16);
      const half8 w1 = *(const half8*)(img2 + ((4 + lq) * 400 + nt * 16 + lc) * 16);
      const f32x4 bias = *(const f32x4*)(b2 + nt * 16 + lq * 4);
#pragma unroll
      for (int g = 0; g < 4; ++g) {
        f32x4 acc = bias;
        acc = __builtin_amdgcn_mfma_f32_16x16x32_f16(w0, hf[g][0], acc, 0, 0, 0);
        acc = __builtin_amdgcn_mfma_f32_16x16x32_f16(w1, hf[g][1], acc, 0, 0, 0);
        const float o0v = o0q[g][r];
#pragma unroll
        for (int rr = 0; rr < 4; ++rr) macc0[g][rr] = fmaf(o0v, acc[rr], macc0[g][rr]);
      }
    }
  }
#pragma unroll
  for (int nt = 20; nt < 24; ++nt) {
    const half8 w0 = *(const half8*)(img2 + ((0 + lq) * 400 + nt * 16 + lc) * 16);
    const half8 w1 = *(const half8*)(img2 + ((4 + lq) * 400 + nt * 16 + lc) * 16);
    const f32x4 bias = *(const f32x4*)(b2 + nt * 16 + lq * 4);
#pragma unroll
    for (int g = 0; g < 4; ++g) {
      f32x4 acc = bias;
      acc = __builtin_amdgcn_mfma_f32_16x16x32_f16(w0, hf[g][0], acc, 0, 0, 0);
      acc = __builtin_amdgcn_mfma_f32_16x16x32_f16(w1, hf[g][1], acc, 0, 0, 0);
      const char* rp0 = ub + (wv * 64 + g * 16 + lc) * kRowB;
      // i = 4*(nt-20) + lq, o = r; o1[i] = ss[i] * sh; ss[i] = o0[i] (f32)
      const float ssv = *(const float*)(rp0 + 16 * (nt - 20) + 4 * lq);
      float pc[3];
#pragma unroll
      for (int c = 0; c < 3; ++c) pc[c] = ssv * shv[g][c];
#pragma unroll
      for (int r = 0; r < 4; ++r)
#pragma unroll
        for (int c = 0; c < 3; ++c)
          macc1[g][r][c] = fmaf(pc[c], acc[r], macc1[g][r][c]);
    }
  }
  {  // nt = 24: i = 16 + lq, o1 row = in_1o
    const int nt = 24;
    const half8 w0 = *(const half8*)(img2 + ((0 + lq) * 400 + nt * 16 + lc) * 16);
    const half8 w1 = *(const half8*)(img2 + ((4 + lq) * 400 + nt * 16 + lc) * 16);
    const f32x4 bias = *(const f32x4*)(b2 + nt * 16 + lq * 4);
#pragma unroll
    for (int g = 0; g < 4; ++g) {
      f32x4 acc = bias;
      acc = __builtin_amdgcn_mfma_f32_16x16x32_f16(w0, hf[g][0], acc, 0, 0, 0);
      acc = __builtin_amdgcn_mfma_f32_16x16x32_f16(w1, hf[g][1], acc, 0, 0, 0);
#pragma unroll
      for (int r = 0; r < 4; ++r)
#pragma unroll
        for (int c = 0; c < 3; ++c)
          macc1[g][r][c] = fmaf(v1h[g][c], acc[r], macc1[g][r][c]);
    }
  }

  // ---- finish msg1 (reduce i-partition across lq groups), scale, write msg rows ----
#pragma unroll
  for (int g = 0; g < 4; ++g)
#pragma unroll
    for (int r = 0; r < 4; ++r)
#pragma unroll
      for (int c = 0; c < 3; ++c) {
        float x = macc1[g][r][c];
        x += __shfl_xor(x, 16);
        x += __shfl_xor(x, 32);
        macc1[g][r][c] = x * kInvSqrt20;
      }
#pragma unroll
  for (int g = 0; g < 4; ++g) {
    char* rp = ub + (wv * 64 + g * 16 + lc) * kRowB;
    *(f32x4*)(rp + lq * 16) =
        f32x4{macc0[g][0] * kInvSqrt20, macc0[g][1] * kInvSqrt20,
              macc0[g][2] * kInvSqrt20, macc0[g][3] * kInvSqrt20};
    f32x4 m1;
    if (lq == 1)
      m1 = f32x4{macc1[g][0][0], macc1[g][0][1], macc1[g][0][2], macc1[g][1][0]};
    else if (lq == 2)
      m1 = f32x4{macc1[g][1][1], macc1[g][1][2], macc1[g][2][0], macc1[g][2][1]};
    else
      m1 = f32x4{macc1[g][2][2], macc1[g][3][0], macc1[g][3][1], macc1[g][3][2]};
    if (lq != 0) *(f32x4*)(rp + 48 + lq * 16) = m1;
  }

  // ---- read back own msg (packed to f16x2), segmented wave reduce in f16 ----
  h2 hm[14];
  {
    const char* rp = ub + tid * kRowB;
#pragma unroll
    for (int c = 0; c < 7; ++c) {
      const f32x4 v = *(const f32x4*)(rp + c * 16);
      hm[c * 2 + 0] = h2{(_Float16)v[0], (_Float16)v[1]};
      hm[c * 2 + 1] = h2{(_Float16)v[2], (_Float16)v[3]};
    }
  }
#pragma unroll
  for (int d = 1; d < 64; d <<= 1) {
    const int od = __shfl_down(dstv, d);
    const bool same = (lane + d < 64) && (od == dstv);
#pragma unroll
    for (int j = 0; j < 14; j++) {
      int u;
      __builtin_memcpy(&u, &hm[j], 4);
      u = __shfl_down(u, d);
      h2 o;
      __builtin_memcpy(&o, &u, 4);
      if (same) hm[j] += o;  // v_pk_add_f16
    }
  }
  const int pd = __shfl_up(dstv, 1);
  if ((lane == 0 || pd != dstv) && dstv >= 0) {
    // pre-normalize: agg was seeded with node_attr; adding msg/cnt completes
    // out = node_attr + (segment-sum)/cnt without a finalize pass.
    const float rc = 1.0f / fmaxf((float)cnt[dstv], 1.0f);
    float* ap = agg + (size_t)dstv * kAttr;
#pragma unroll
    for (int j = 0; j < 14; j++) {
      atomicAdd(ap + 2 * j + 0, (float)hm[j][0] * rc);
      atomicAdd(ap + 2 * j + 1, (float)hm[j][1] * rc);
    }
  }
}

extern "C" void kernel_launch(void* const* d_in, const int* in_sizes, int n_in,
                              void* d_out, int out_size, void* d_ws, size_t ws_size,
                              hipStream_t stream) {
  const float* node_attr = (const float*)d_in[0];
  const float* pos = (const float*)d_in[1];
  const float* W1 = (const float*)d_in[2];
  const float* b1 = (const float*)d_in[3];
  const float* W2 = (const float*)d_in[4];
  const float* b2 = (const float*)d_in[5];
  const int* edge_index = (const int*)d_in[6];

  const int N = in_sizes[0] / kAttr;
  const int E = in_sizes[6] / 2;

  // ws layout: [img1][img2][cnt N][node_start N][rank E][sedge E int2] ~4.0MB
  char* wsc = (char*)d_ws;
  unsigned short* img1 = (unsigned short*)wsc;
  unsigned short* img2 = (unsigned short*)(wsc + kImg1Bytes);
  int* cnt = (int*)(wsc + kImg1Bytes + kImg2Bytes);
  int* node_start = cnt + N;
  int* rank = node_start + N;
  int2* sedge = (int2*)(rank + E);

  float* agg = (float*)d_out;
  const int aggN4 = out_size / 4;
  const int eblocks = (E + 255) / 256;

  // 5 dispatches, all plain (r9: no grid.sync; r8: no mega-fuse; r12: no
  // finalize; r13: one atomic pass, rank-addressed scatter).
  init_kernel<<<512, 256, 0, stream>>>(W1, W2, node_attr, img1, img2, cnt, agg,
                                       aggN4, N);
  hist_rank_kernel<<<eblocks, 256, 0, stream>>>(edge_index, cnt, rank, E);
  scan_kernel<<<1, 256, 0, stream>>>(cnt, node_start, N);
  scatter_kernel<<<eblocks, 256, 0, stream>>>(edge_index, node_start, rank,
                                              sedge, E);
  tfn_mfma_kernel<<<eblocks, 256, 0, stream>>>(
      node_attr, pos, b1, b2, (const char*)img1, (const char*)img2,
      sedge, cnt, agg, E);
}

// Round 15
// 410.966 us; speedup vs baseline: 1.0022x; 1.0022x over previous
//
#include <hip/hip_runtime.h>
#include <math.h>

typedef _Float16 half8 __attribute__((ext_vector_type(8)));
typedef float f32x4 __attribute__((ext_vector_type(4)));
typedef unsigned int u32x4 __attribute__((ext_vector_type(4)));
typedef unsigned int u32x2 __attribute__((ext_vector_type(2)));

namespace {
constexpr int kNS = 16;
constexpr int kNV = 4;
constexpr int kNG = 50;
constexpr int kHID = 64;
constexpr int kAttr = 28;                 // NS + 3*NV
constexpr int kWNUM = 400;
constexpr float kStep = 5.0f / 49.0f;
constexpr float kCoeff = -0.5f / (kStep * kStep);
constexpr float kSqrt3 = 1.7320508075688772f;
constexpr float kInvSqrt3 = 0.57735026918962576f;
constexpr float kInvSqrt20 = 0.22360679774997896f;
// Row = 208 B (13 granules): 52 words == 20 mod 32 -> 16 rows spread over 8
// bank-offset classes (2 lanes/bank = free). No XOR swizzle (r3 lesson).
constexpr int kRowB = 208;
constexpr int kImg1Bytes = 96 * 64 * 2;   // 12288
constexpr int kImg2Bytes = 64 * 400 * 2;  // 51200
}  // namespace

// f16 end-to-end (r6-r13: absmax 0.016-0.09 vs threshold 0.101).
// (_Float16) cast = hardware v_cvt_f16_f32 RNE (r5: hip bf16 helpers truncate).
// r14 lesson: NEVER memcpy/address-cast elements of a register array (h2
// hm[14] + memcpy -> scratch: FETCH 13.5->398MB, 5.6x slowdown). Reduce on
// plain float arrays with __shfl_down only.
__device__ __forceinline__ unsigned short f2h(float x) {
  _Float16 h = (_Float16)x;
  unsigned short r;
  __builtin_memcpy(&r, &h, 2);
  return r;
}
__device__ __forceinline__ unsigned pack2(float lo, float hi) {
  return (unsigned)f2h(lo) | ((unsigned)f2h(hi) << 16);
}

// ---------- A: fused init (agg = node_attr; cnt = 0; f16 weight images) ------
__global__ __launch_bounds__(256) void init_kernel(
    const float* __restrict__ W1, const float* __restrict__ W2,
    const float* __restrict__ node_attr,
    unsigned short* __restrict__ img1, unsigned short* __restrict__ img2,
    int* __restrict__ cnt, float* __restrict__ agg, int aggN4, int N) {
  const int gtid = blockIdx.x * 256 + threadIdx.x;
  const int gsz = gridDim.x * 256;
  f32x4* agg4 = (f32x4*)agg;
  const f32x4* na4 = (const f32x4*)node_attr;
  for (int i = gtid; i < aggN4; i += gsz) agg4[i] = na4[i];
  for (int i = gtid; i < N; i += gsz) cnt[i] = 0;
  // img layout: element (k, n) at byte ((k>>3)*W + n)*16 + 2*(k&7)
  for (int i = gtid; i < 96 * 64 + 64 * 400; i += gsz) {
    if (i < 96 * 64) {
      const int m = i >> 6, n = i & 63;
      float v = 0.0f;
      if (m < 50) v = W1[m * 64 + n];                        // gaussian rows
      else if (m >= 56 && m < 88) v = W1[(m - 6) * 64 + n];  // ss, ds rows
      img1[((m >> 3) * 64 + n) * 8 + (m & 7)] = f2h(v);
    } else {
      const int j = i - 96 * 64;
      const int m = j / 400, n = j % 400;
      img2[((m >> 3) * 400 + n) * 8 + (m & 7)] = f2h(W2[m * 400 + n]);
    }
  }
}

// ---------- B: histogram of dst + per-edge rank (the ONLY atomic pass) -------
__global__ __launch_bounds__(256) void hist_rank_kernel(
    const int* __restrict__ edge_index, int* __restrict__ cnt,
    int* __restrict__ rank, int E) {
  const int e = blockIdx.x * blockDim.x + threadIdx.x;
  if (e >= E) return;
  rank[e] = atomicAdd(cnt + edge_index[E + e], 1);
}

// ---------- C: exclusive scan cnt -> node_start (single block, wave-scan) ----
__global__ __launch_bounds__(256) void scan_kernel(
    const int* __restrict__ cnt, int* __restrict__ node_start, int N) {
  __shared__ int wsum[4];
  const int tid = threadIdx.x;
  const int lane = tid & 63;
  const int wv = tid >> 6;
  const int n4 = (N + 3) >> 2;
  const int tiles = (n4 + 255) / 256;
  int running = 0;
  for (int k = 0; k < tiles; ++k) {
    const int i4 = k * 256 + tid;
    int4 v = {0, 0, 0, 0};
    const int base = i4 * 4;
    if (i4 < n4) {
      if (base + 3 < N) {
        v = *(const int4*)(cnt + base);
      } else {
        if (base + 0 < N) v.x = cnt[base + 0];
        if (base + 1 < N) v.y = cnt[base + 1];
        if (base + 2 < N) v.z = cnt[base + 2];
      }
    }
    const int e1 = v.x, e2 = v.x + v.y, e3 = e2 + v.z, s4 = e3 + v.w;
    int incl = s4;
#pragma unroll
    for (int d = 1; d < 64; d <<= 1) {
      const int y = __shfl_up(incl, d);
      if (lane >= d) incl += y;
    }
    if (lane == 63) wsum[wv] = incl;
    __syncthreads();
    int wbase = 0;
#pragma unroll
    for (int w = 0; w < 4; ++w) wbase += (w < wv) ? wsum[w] : 0;
    const int block_total = wsum[0] + wsum[1] + wsum[2] + wsum[3];
    const int tbase = running + wbase + (incl - s4);
    if (i4 < n4) {
      if (base + 0 < N) node_start[base + 0] = tbase;
      if (base + 1 < N) node_start[base + 1] = tbase + e1;
      if (base + 2 < N) node_start[base + 2] = tbase + e2;
      if (base + 3 < N) node_start[base + 3] = tbase + e3;
    }
    running += block_total;
    __syncthreads();  // wsum reused next tile
  }
}

// ---------- D: scatter (ATOMIC-FREE: slot = node_start[d] + rank[e]) ---------
__global__ __launch_bounds__(256) void scatter_kernel(
    const int* __restrict__ edge_index, const int* __restrict__ node_start,
    const int* __restrict__ rank, int2* __restrict__ sedge, int E) {
  const int e = blockIdx.x * blockDim.x + threadIdx.x;
  if (e >= E) return;
  const int s = edge_index[e];
  const int d = edge_index[E + e];
  sedge[node_start[d] + rank[e]] = int2{s, d};
}

// ---------- E: main MFMA edge kernel ----------
// r15 = r13 body + the two benign r14 read batchings (o0 via q-outer b128,
// sh/v1 via 16B-aligned b128), with the r14 f16-packed reduce REVERTED to
// r13's plain float msg[28] + __shfl_down (no address-taking -> no scratch).
// ub row (208B) timeline: ef(96 f16, chunks 0..11) -> h(chunks 0..7) +
// sh/v1 stash(chunks 8..12) -> o0 f32(chunks 0..4, after hf hoist) ->
// msg(28 f32, chunks 0..6). LDS 53248 B => 3 blocks/CU. All LDS wave-local.
__global__ __launch_bounds__(256, 3) void tfn_mfma_kernel(
    const float* __restrict__ node_attr, const float* __restrict__ pos,
    const float* __restrict__ b1, const float* __restrict__ b2,
    const char* __restrict__ img1, const char* __restrict__ img2,
    const int2* __restrict__ sedge, const int* __restrict__ cnt,
    float* __restrict__ agg, int E) {
  __shared__ __align__(16) char ub[256 * kRowB];   // 53248 B (3 blocks/CU)

  const int tid = threadIdx.x;
  const int t = blockIdx.x * 256 + tid;
  const int lane = tid & 63;
  const int wv = tid >> 6;
  const int lc = lane & 15, lq = lane >> 4;

  const bool valid = (t < E);
  int src = 0, dstv = -1;
  if (valid) {
    const int2 se = sedge[t];
    src = se.x;
    dstv = se.y;
  }
  const int dn = valid ? dstv : 0;

  // ---- geometry ----
  const float psx = pos[src * 3 + 0], psy = pos[src * 3 + 1], psz = pos[src * 3 + 2];
  const float pdx = pos[dn * 3 + 0], pdy = pos[dn * 3 + 1], pdz = pos[dn * 3 + 2];
  const float vx = pdx - psx, vy = pdy - psy, vz = pdz - psz;
  const float dist = sqrtf(vx * vx + vy * vy + vz * vz);
  const float rinv = 1.0f / fmaxf(dist, 1e-8f);
  const float sh0 = kSqrt3 * (vy * rinv);
  const float sh1 = kSqrt3 * (vz * rinv);
  const float sh2 = kSqrt3 * (vx * rinv);

  const float* nas = node_attr + (size_t)src * kAttr;
  const float* nad = node_attr + (size_t)dn * kAttr;
  const float4 sa = *(const float4*)(nas + 0);
  const float4 sb = *(const float4*)(nas + 4);
  const float4 sc4 = *(const float4*)(nas + 8);
  const float4 sd4 = *(const float4*)(nas + 12);
  const float4 va = *(const float4*)(nas + 16);
  const float4 vb = *(const float4*)(nas + 20);
  const float4 vc = *(const float4*)(nas + 24);
  const float4 da = *(const float4*)(nad + 0);
  const float4 db = *(const float4*)(nad + 4);
  const float4 dc4 = *(const float4*)(nad + 8);
  const float4 dd4 = *(const float4*)(nad + 12);

  char* myrow = ub + tid * kRowB;

  // ---- write ef row (96 f16): [gauss50 | 0x6 | ss16 | ds16 | 0x8] ----
  {
    const float base = dist + 1e-6f;
#pragma unroll
    for (int c = 0; c < 6; ++c) {
      unsigned p[4];
#pragma unroll
      for (int u = 0; u < 4; ++u) {
        const int k = c * 8 + u * 2;
        const float d0 = base - (float)k * kStep;
        const float d1 = base - (float)(k + 1) * kStep;
        p[u] = pack2(__expf(kCoeff * d0 * d0), __expf(kCoeff * d1 * d1));
      }
      *(u32x4*)(myrow + c * 16) = u32x4{p[0], p[1], p[2], p[3]};
    }
    const float d0 = base - 48.0f * kStep, d1 = base - 49.0f * kStep;
    *(u32x4*)(myrow + 6 * 16) =
        u32x4{pack2(__expf(kCoeff * d0 * d0), __expf(kCoeff * d1 * d1)), 0u, 0u, 0u};
    *(u32x4*)(myrow + 7 * 16) =
        u32x4{pack2(sa.x, sa.y), pack2(sa.z, sa.w), pack2(sb.x, sb.y), pack2(sb.z, sb.w)};
    *(u32x4*)(myrow + 8 * 16) =
        u32x4{pack2(sc4.x, sc4.y), pack2(sc4.z, sc4.w), pack2(sd4.x, sd4.y), pack2(sd4.z, sd4.w)};
    *(u32x4*)(myrow + 9 * 16) =
        u32x4{pack2(da.x, da.y), pack2(da.z, da.w), pack2(db.x, db.y), pack2(db.z, db.w)};
    *(u32x4*)(myrow + 10 * 16) =
        u32x4{pack2(dc4.x, dc4.y), pack2(dc4.z, dc4.w), pack2(dd4.x, dd4.y), pack2(dd4.z, dd4.w)};
    *(u32x4*)(myrow + 11 * 16) = u32x4{0u, 0u, 0u, 0u};
  }

  const float v1f[12] = {va.x, va.y, va.z, va.w, vb.x, vb.y, vb.z, vb.w,
                         vc.x, vc.y, vc.z, vc.w};

  // ---- hoist ef fragments (B-operand: lane holds ef[e=g*16+lc][k=(ks*4+lq)*8+j]) ----
  half8 eff[4][3];
#pragma unroll
  for (int g = 0; g < 4; ++g) {
    const char* rp = ub + (wv * 64 + g * 16 + lc) * kRowB;
#pragma unroll
    for (int ks = 0; ks < 3; ++ks)
      eff[g][ks] = *(const half8*)(rp + (ks * 4 + lq) * 16);
  }

  // ---- stash sh/v1 as f32, 16B-aligned per triple (chunks 8..12) ----
  *(f32x4*)(myrow + 8 * 16) = f32x4{sh0, sh1, sh2, 0.0f};
  *(f32x4*)(myrow + 9 * 16) = f32x4{v1f[0], v1f[1], v1f[2], 0.0f};
  *(f32x4*)(myrow + 10 * 16) = f32x4{v1f[3], v1f[4], v1f[5], 0.0f};
  *(f32x4*)(myrow + 11 * 16) = f32x4{v1f[6], v1f[7], v1f[8], 0.0f};
  *(f32x4*)(myrow + 12 * 16) = f32x4{v1f[9], v1f[10], v1f[11], 0.0f};

  // ---- MFMA-1: h[n][e] = relu(b1[n] + sum_k W1p[k][n] ef[e][k]) ----
#pragma unroll
  for (int nt = 0; nt < 4; ++nt) {
    const half8 a0 = *(const half8*)(img1 + ((0 + lq) * 64 + nt * 16 + lc) * 16);
    const half8 a1 = *(const half8*)(img1 + ((4 + lq) * 64 + nt * 16 + lc) * 16);
    const half8 a2 = *(const half8*)(img1 + ((8 + lq) * 64 + nt * 16 + lc) * 16);
    const f32x4 bias = *(const f32x4*)(b1 + nt * 16 + lq * 4);
#pragma unroll
    for (int g = 0; g < 4; ++g) {
      f32x4 acc = bias;
      acc = __builtin_amdgcn_mfma_f32_16x16x32_f16(a0, eff[g][0], acc, 0, 0, 0);
      acc = __builtin_amdgcn_mfma_f32_16x16x32_f16(a1, eff[g][1], acc, 0, 0, 0);
      acc = __builtin_amdgcn_mfma_f32_16x16x32_f16(a2, eff[g][2], acc, 0, 0, 0);
      const unsigned p0 = pack2(fmaxf(acc[0], 0.0f), fmaxf(acc[1], 0.0f));
      const unsigned p1 = pack2(fmaxf(acc[2], 0.0f), fmaxf(acc[3], 0.0f));
      const int row = wv * 64 + g * 16 + lc;
      // n = nt*16 + lq*4 + r -> byte 2n = nt*32 + lq*8
      *(u32x2*)(ub + row * kRowB + nt * 32 + lq * 8) = u32x2{p0, p1};
    }
  }

  // ---- load h fragments (B-operand: lane holds h[k][e=g*16+lc]) ----
  half8 hf[4][2];
#pragma unroll
  for (int g = 0; g < 4; ++g) {
    const char* rp = ub + (wv * 64 + g * 16 + lc) * kRowB;
    hf[g][0] = *(const half8*)(rp + (0 + lq) * 16);
    hf[g][1] = *(const half8*)(rp + (4 + lq) * 16);
  }

  // ---- hoist per-edge sh / v1 via b128 (8 reads; was 24 scalar) ----
  float shv[4][3], v1h[4][3];
#pragma unroll
  for (int g = 0; g < 4; ++g) {
    const char* rp = ub + (wv * 64 + g * 16 + lc) * kRowB;
    const f32x4 s4 = *(const f32x4*)(rp + 128);
    shv[g][0] = s4[0]; shv[g][1] = s4[1]; shv[g][2] = s4[2];
    const f32x4 v4 = *(const f32x4*)(rp + 144 + 16 * lq);
    v1h[g][0] = v4[0]; v1h[g][1] = v4[1]; v1h[g][2] = v4[2];
  }

  // ---- o0[20] as f32 into chunks 0..4 (h region dead now that hf is in regs) ----
  {
    const float t0 = (v1f[0] * sh0 + v1f[1] * sh1 + v1f[2] * sh2) * kInvSqrt3;
    const float t1 = (v1f[3] * sh0 + v1f[4] * sh1 + v1f[5] * sh2) * kInvSqrt3;
    const float t2 = (v1f[6] * sh0 + v1f[7] * sh1 + v1f[8] * sh2) * kInvSqrt3;
    const float t3 = (v1f[9] * sh0 + v1f[10] * sh1 + v1f[11] * sh2) * kInvSqrt3;
    *(f32x4*)(myrow + 0) = f32x4{sa.x, sa.y, sa.z, sa.w};
    *(f32x4*)(myrow + 16) = f32x4{sb.x, sb.y, sb.z, sb.w};
    *(f32x4*)(myrow + 32) = f32x4{sc4.x, sc4.y, sc4.z, sc4.w};
    *(f32x4*)(myrow + 48) = f32x4{sd4.x, sd4.y, sd4.z, sd4.w};
    *(f32x4*)(myrow + 64) = f32x4{t0, t1, t2, t3};
  }

  // ---- MFMA-2 + fused contraction. D[n][e]: lane owns edge lc, n = 16nt+4lq+r ----
  float macc0[4][4] = {};
  float macc1[4][4][3] = {};

  // nt = 0..19 q-outer: one b128 o0 load per (q,g); compile-time extracts.
#pragma unroll
  for (int q = 0; q < 5; ++q) {
    f32x4 o0q[4];
#pragma unroll
    for (int g = 0; g < 4; ++g)
      o0q[g] = *(const f32x4*)(ub + (wv * 64 + g * 16 + lc) * kRowB + 16 * q);
#pragma unroll
    for (int r = 0; r < 4; ++r) {
      const int nt = q * 4 + r;
      const half8 w0 = *(const half8*)(img2 + ((0 + lq) * 400 + nt * 16 + lc) * 16);
      const half8 w1 = *(const half8*)(img2 + ((4 + lq) * 400 + nt * 16 + lc) * 16);
      const f32x4 bias = *(const f32x4*)(b2 + nt * 16 + lq * 4);
#pragma unroll
      for (int g = 0; g < 4; ++g) {
        f32x4 acc = bias;
        acc = __builtin_amdgcn_mfma_f32_16x16x32_f16(w0, hf[g][0], acc, 0, 0, 0);
        acc = __builtin_amdgcn_mfma_f32_16x16x32_f16(w1, hf[g][1], acc, 0, 0, 0);
        const float o0v = o0q[g][r];
#pragma unroll
        for (int rr = 0; rr < 4; ++rr) macc0[g][rr] = fmaf(o0v, acc[rr], macc0[g][rr]);
      }
    }
  }
#pragma unroll
  for (int nt = 20; nt < 24; ++nt) {
    const half8 w0 = *(const half8*)(img2 + ((0 + lq) * 400 + nt * 16 + lc) * 16);
    const half8 w1 = *(const half8*)(img2 + ((4 + lq) * 400 + nt * 16 + lc) * 16);
    const f32x4 bias = *(const f32x4*)(b2 + nt * 16 + lq * 4);
#pragma unroll
    for (int g = 0; g < 4; ++g) {
      f32x4 acc = bias;
      acc = __builtin_amdgcn_mfma_f32_16x16x32_f16(w0, hf[g][0], acc, 0, 0, 0);
      acc = __builtin_amdgcn_mfma_f32_16x16x32_f16(w1, hf[g][1], acc, 0, 0, 0);
      const char* rp0 = ub + (wv * 64 + g * 16 + lc) * kRowB;
      // i = 4*(nt-20) + lq, o = r; o1[i] = ss[i] * sh; ss[i] = o0[i] (f32)
      const float ssv = *(const float*)(rp0 + 16 * (nt - 20) + 4 * lq);
      float pc[3];
#pragma unroll
      for (int c = 0; c < 3; ++c) pc[c] = ssv * shv[g][c];
#pragma unroll
      for (int r = 0; r < 4; ++r)
#pragma unroll
        for (int c = 0; c < 3; ++c)
          macc1[g][r][c] = fmaf(pc[c], acc[r], macc1[g][r][c]);
    }
  }
  {  // nt = 24: i = 16 + lq, o1 row = in_1o
    const int nt = 24;
    const half8 w0 = *(const half8*)(img2 + ((0 + lq) * 400 + nt * 16 + lc) * 16);
    const half8 w1 = *(const half8*)(img2 + ((4 + lq) * 400 + nt * 16 + lc) * 16);
    const f32x4 bias = *(const f32x4*)(b2 + nt * 16 + lq * 4);
#pragma unroll
    for (int g = 0; g < 4; ++g) {
      f32x4 acc = bias;
      acc = __builtin_amdgcn_mfma_f32_16x16x32_f16(w0, hf[g][0], acc, 0, 0, 0);
      acc = __builtin_amdgcn_mfma_f32_16x16x32_f16(w1, hf[g][1], acc, 0, 0, 0);
#pragma unroll
      for (int r = 0; r < 4; ++r)
#pragma unroll
        for (int c = 0; c < 3; ++c)
          macc1[g][r][c] = fmaf(v1h[g][c], acc[r], macc1[g][r][c]);
    }
  }

  // ---- finish msg1 (reduce i-partition across lq groups), scale, write msg rows ----
#pragma unroll
  for (int g = 0; g < 4; ++g)
#pragma unroll
    for (int r = 0; r < 4; ++r)
#pragma unroll
      for (int c = 0; c < 3; ++c) {
        float x = macc1[g][r][c];
        x += __shfl_xor(x, 16);
        x += __shfl_xor(x, 32);
        macc1[g][r][c] = x * kInvSqrt20;
      }
#pragma unroll
  for (int g = 0; g < 4; ++g) {
    char* rp = ub + (wv * 64 + g * 16 + lc) * kRowB;
    *(f32x4*)(rp + lq * 16) =
        f32x4{macc0[g][0] * kInvSqrt20, macc0[g][1] * kInvSqrt20,
              macc0[g][2] * kInvSqrt20, macc0[g][3] * kInvSqrt20};
    f32x4 m1;
    if (lq == 1)
      m1 = f32x4{macc1[g][0][0], macc1[g][0][1], macc1[g][0][2], macc1[g][1][0]};
    else if (lq == 2)
      m1 = f32x4{macc1[g][1][1], macc1[g][1][2], macc1[g][2][0], macc1[g][2][1]};
    else
      m1 = f32x4{macc1[g][2][2], macc1[g][3][0], macc1[g][3][1], macc1[g][3][2]};
    if (lq != 0) *(f32x4*)(rp + 48 + lq * 16) = m1;
  }

  // ---- read back own msg, segmented wave reduction, one atomic per segment head ----
  float msg[28];
  {
    const char* rp = ub + tid * kRowB;
#pragma unroll
    for (int c = 0; c < 7; ++c) {
      const f32x4 v = *(const f32x4*)(rp + c * 16);
      msg[c * 4 + 0] = v[0];
      msg[c * 4 + 1] = v[1];
      msg[c * 4 + 2] = v[2];
      msg[c * 4 + 3] = v[3];
    }
  }
#pragma unroll
  for (int d = 1; d < 64; d <<= 1) {
    const int od = __shfl_down(dstv, d);
    const bool same = (lane + d < 64) && (od == dstv);
#pragma unroll
    for (int j = 0; j < 28; j++) {
      const float ov = __shfl_down(msg[j], d);
      if (same) msg[j] += ov;
    }
  }
  const int pd = __shfl_up(dstv, 1);
  if ((lane == 0 || pd != dstv) && dstv >= 0) {
    // pre-normalize: agg was seeded with node_attr; adding msg/cnt completes
    // out = node_attr + (segment-sum)/cnt without a finalize pass.
    const float rc = 1.0f / fmaxf((float)cnt[dstv], 1.0f);
    float* ap = agg + (size_t)dstv * kAttr;
#pragma unroll
    for (int j = 0; j < 28; j++) atomicAdd(ap + j, msg[j] * rc);
  }
}

extern "C" void kernel_launch(void* const* d_in, const int* in_sizes, int n_in,
                              void* d_out, int out_size, void* d_ws, size_t ws_size,
                              hipStream_t stream) {
  const float* node_attr = (const float*)d_in[0];
  const float* pos = (const float*)d_in[1];
  const float* W1 = (const float*)d_in[2];
  const float* b1 = (const float*)d_in[3];
  const float* W2 = (const float*)d_in[4];
  const float* b2 = (const float*)d_in[5];
  const int* edge_index = (const int*)d_in[6];

  const int N = in_sizes[0] / kAttr;
  const int E = in_sizes[6] / 2;

  // ws layout: [img1][img2][cnt N][node_start N][rank E][sedge E int2] ~4.0MB
  char* wsc = (char*)d_ws;
  unsigned short* img1 = (unsigned short*)wsc;
  unsigned short* img2 = (unsigned short*)(wsc + kImg1Bytes);
  int* cnt = (int*)(wsc + kImg1Bytes + kImg2Bytes);
  int* node_start = cnt + N;
  int* rank = node_start + N;
  int2* sedge = (int2*)(rank + E);

  float* agg = (float*)d_out;
  const int aggN4 = out_size / 4;
  const int eblocks = (E + 255) / 256;

  // 5 dispatches, all plain (r9: no grid.sync; r8: no mega-fuse; r12: no
  // finalize; r13: one atomic pass, rank-addressed scatter).
  init_kernel<<<512, 256, 0, stream>>>(W1, W2, node_attr, img1, img2, cnt, agg,
                                       aggN4, N);
  hist_rank_kernel<<<eblocks, 256, 0, stream>>>(edge_index, cnt, rank, E);
  scan_kernel<<<1, 256, 0, stream>>>(cnt, node_start, N);
  scatter_kernel<<<eblocks, 256, 0, stream>>>(edge_index, node_start, rank,
                                              sedge, E);
  tfn_mfma_kernel<<<eblocks, 256, 0, stream>>>(
      node_attr, pos, b1, b2, (const char*)img1, (const char*)img2,
      sedge, cnt, agg, E);
}

// Round 16
// 107.487 us; speedup vs baseline: 3.8317x; 3.8234x over previous
//
#include <hip/hip_runtime.h>
#include <math.h>

typedef _Float16 half8 __attribute__((ext_vector_type(8)));
typedef float f32x4 __attribute__((ext_vector_type(4)));
typedef unsigned int u32x4 __attribute__((ext_vector_type(4)));
typedef unsigned int u32x2 __attribute__((ext_vector_type(2)));

namespace {
constexpr int kNS = 16;
constexpr int kNV = 4;
constexpr int kNG = 50;
constexpr int kHID = 64;
constexpr int kAttr = 28;                 // NS + 3*NV
constexpr int kWNUM = 400;
constexpr float kStep = 5.0f / 49.0f;
constexpr float kCoeff = -0.5f / (kStep * kStep);
constexpr float kSqrt3 = 1.7320508075688772f;
constexpr float kInvSqrt3 = 0.57735026918962576f;
constexpr float kInvSqrt20 = 0.22360679774997896f;
// Row = 208 B (13 granules): 52 words == 20 mod 32 -> 16 rows spread over 8
// bank-offset classes (2 lanes/bank = free). No XOR swizzle (r3 lesson).
constexpr int kRowB = 208;
constexpr int kImg1Bytes = 96 * 64 * 2;   // 12288
constexpr int kImg2Bytes = 64 * 400 * 2;  // 51200
}  // namespace

// f16 end-to-end (r6-r13: absmax 0.016-0.09 vs threshold 0.101).
// (_Float16) cast = hardware v_cvt_f16_f32 RNE (r5: hip bf16 helpers truncate).
// r14/r15 lessons (both reverted here): (a) never memcpy/address-cast elements
// of a register array (scratch spill); (b) the q-outer FULL unroll of MFMA-2
// exploded live ranges (w0/w1 hoisting) -> 2.4KB/thread scratch, 5.6x slower.
// r13's partial `#pragma unroll 5` + scalar o0 reads is the proven form.
__device__ __forceinline__ unsigned short f2h(float x) {
  _Float16 h = (_Float16)x;
  unsigned short r;
  __builtin_memcpy(&r, &h, 2);
  return r;
}
__device__ __forceinline__ unsigned pack2(float lo, float hi) {
  return (unsigned)f2h(lo) | ((unsigned)f2h(hi) << 16);
}

// ---------- A: fused init (agg = node_attr; cnt = 0; f16 weight images) ------
__global__ __launch_bounds__(256) void init_kernel(
    const float* __restrict__ W1, const float* __restrict__ W2,
    const float* __restrict__ node_attr,
    unsigned short* __restrict__ img1, unsigned short* __restrict__ img2,
    int* __restrict__ cnt, float* __restrict__ agg, int aggN4, int N) {
  const int gtid = blockIdx.x * 256 + threadIdx.x;
  const int gsz = gridDim.x * 256;
  f32x4* agg4 = (f32x4*)agg;
  const f32x4* na4 = (const f32x4*)node_attr;
  for (int i = gtid; i < aggN4; i += gsz) agg4[i] = na4[i];
  for (int i = gtid; i < N; i += gsz) cnt[i] = 0;
  // img layout: element (k, n) at byte ((k>>3)*W + n)*16 + 2*(k&7)
  for (int i = gtid; i < 96 * 64 + 64 * 400; i += gsz) {
    if (i < 96 * 64) {
      const int m = i >> 6, n = i & 63;
      float v = 0.0f;
      if (m < 50) v = W1[m * 64 + n];                        // gaussian rows
      else if (m >= 56 && m < 88) v = W1[(m - 6) * 64 + n];  // ss, ds rows
      img1[((m >> 3) * 64 + n) * 8 + (m & 7)] = f2h(v);
    } else {
      const int j = i - 96 * 64;
      const int m = j / 400, n = j % 400;
      img2[((m >> 3) * 400 + n) * 8 + (m & 7)] = f2h(W2[m * 400 + n]);
    }
  }
}

// ---------- B: histogram of dst + per-edge rank (the ONLY atomic pass) -------
__global__ __launch_bounds__(256) void hist_rank_kernel(
    const int* __restrict__ edge_index, int* __restrict__ cnt,
    int* __restrict__ rank, int E) {
  const int e = blockIdx.x * blockDim.x + threadIdx.x;
  if (e >= E) return;
  rank[e] = atomicAdd(cnt + edge_index[E + e], 1);
}

// ---------- C: exclusive scan cnt -> node_start (single block, wave-scan) ----
__global__ __launch_bounds__(256) void scan_kernel(
    const int* __restrict__ cnt, int* __restrict__ node_start, int N) {
  __shared__ int wsum[4];
  const int tid = threadIdx.x;
  const int lane = tid & 63;
  const int wv = tid >> 6;
  const int n4 = (N + 3) >> 2;
  const int tiles = (n4 + 255) / 256;
  int running = 0;
  for (int k = 0; k < tiles; ++k) {
    const int i4 = k * 256 + tid;
    int4 v = {0, 0, 0, 0};
    const int base = i4 * 4;
    if (i4 < n4) {
      if (base + 3 < N) {
        v = *(const int4*)(cnt + base);
      } else {
        if (base + 0 < N) v.x = cnt[base + 0];
        if (base + 1 < N) v.y = cnt[base + 1];
        if (base + 2 < N) v.z = cnt[base + 2];
      }
    }
    const int e1 = v.x, e2 = v.x + v.y, e3 = e2 + v.z, s4 = e3 + v.w;
    int incl = s4;
#pragma unroll
    for (int d = 1; d < 64; d <<= 1) {
      const int y = __shfl_up(incl, d);
      if (lane >= d) incl += y;
    }
    if (lane == 63) wsum[wv] = incl;
    __syncthreads();
    int wbase = 0;
#pragma unroll
    for (int w = 0; w < 4; ++w) wbase += (w < wv) ? wsum[w] : 0;
    const int block_total = wsum[0] + wsum[1] + wsum[2] + wsum[3];
    const int tbase = running + wbase + (incl - s4);
    if (i4 < n4) {
      if (base + 0 < N) node_start[base + 0] = tbase;
      if (base + 1 < N) node_start[base + 1] = tbase + e1;
      if (base + 2 < N) node_start[base + 2] = tbase + e2;
      if (base + 3 < N) node_start[base + 3] = tbase + e3;
    }
    running += block_total;
    __syncthreads();  // wsum reused next tile
  }
}

// ---------- D: scatter (ATOMIC-FREE: slot = node_start[d] + rank[e]) ---------
__global__ __launch_bounds__(256) void scatter_kernel(
    const int* __restrict__ edge_index, const int* __restrict__ node_start,
    const int* __restrict__ rank, int2* __restrict__ sedge, int E) {
  const int e = blockIdx.x * blockDim.x + threadIdx.x;
  if (e >= E) return;
  const int s = edge_index[e];
  const int d = edge_index[E + e];
  sedge[node_start[d] + rank[e]] = int2{s, d};
}

// ---------- E: main MFMA edge kernel (EXACT r13 body — proven 68us) ----------
// Per wave: 64 edges (4 groups of 16). All LDS traffic is wave-local; same-
// wave DS ops retire in program order, so the phase overwrites are safe.
// ub row (208B) timeline: ef(96 f16, chunks 0..11) -> h(chunks 0..7) +
// sh/v1 stash(chunks 8..11) -> o0 f32(chunks 0..4, after hf hoist) ->
// msg(28 f32, chunks 0..6). LDS 53248 B => 3 blocks/CU.
// Segment heads scale msg by 1/max(cnt[dst],1) before atomicAdd
// (pre-normalized aggregation; agg pre-seeded with node_attr by init).
__global__ __launch_bounds__(256, 3) void tfn_mfma_kernel(
    const float* __restrict__ node_attr, const float* __restrict__ pos,
    const float* __restrict__ b1, const float* __restrict__ b2,
    const char* __restrict__ img1, const char* __restrict__ img2,
    const int2* __restrict__ sedge, const int* __restrict__ cnt,
    float* __restrict__ agg, int E) {
  __shared__ __align__(16) char ub[256 * kRowB];   // 53248 B (3 blocks/CU)

  const int tid = threadIdx.x;
  const int t = blockIdx.x * 256 + tid;
  const int lane = tid & 63;
  const int wv = tid >> 6;
  const int lc = lane & 15, lq = lane >> 4;

  const bool valid = (t < E);
  int src = 0, dstv = -1;
  if (valid) {
    const int2 se = sedge[t];
    src = se.x;
    dstv = se.y;
  }
  const int dn = valid ? dstv : 0;

  // ---- geometry ----
  const float psx = pos[src * 3 + 0], psy = pos[src * 3 + 1], psz = pos[src * 3 + 2];
  const float pdx = pos[dn * 3 + 0], pdy = pos[dn * 3 + 1], pdz = pos[dn * 3 + 2];
  const float vx = pdx - psx, vy = pdy - psy, vz = pdz - psz;
  const float dist = sqrtf(vx * vx + vy * vy + vz * vz);
  const float rinv = 1.0f / fmaxf(dist, 1e-8f);
  const float sh0 = kSqrt3 * (vy * rinv);
  const float sh1 = kSqrt3 * (vz * rinv);
  const float sh2 = kSqrt3 * (vx * rinv);

  const float* nas = node_attr + (size_t)src * kAttr;
  const float* nad = node_attr + (size_t)dn * kAttr;
  const float4 sa = *(const float4*)(nas + 0);
  const float4 sb = *(const float4*)(nas + 4);
  const float4 sc4 = *(const float4*)(nas + 8);
  const float4 sd4 = *(const float4*)(nas + 12);
  const float4 va = *(const float4*)(nas + 16);
  const float4 vb = *(const float4*)(nas + 20);
  const float4 vc = *(const float4*)(nas + 24);
  const float4 da = *(const float4*)(nad + 0);
  const float4 db = *(const float4*)(nad + 4);
  const float4 dc4 = *(const float4*)(nad + 8);
  const float4 dd4 = *(const float4*)(nad + 12);

  char* myrow = ub + tid * kRowB;

  // ---- write ef row (96 f16): [gauss50 | 0x6 | ss16 | ds16 | 0x8] ----
  {
    const float base = dist + 1e-6f;
#pragma unroll
    for (int c = 0; c < 6; ++c) {
      unsigned p[4];
#pragma unroll
      for (int u = 0; u < 4; ++u) {
        const int k = c * 8 + u * 2;
        const float d0 = base - (float)k * kStep;
        const float d1 = base - (float)(k + 1) * kStep;
        p[u] = pack2(__expf(kCoeff * d0 * d0), __expf(kCoeff * d1 * d1));
      }
      *(u32x4*)(myrow + c * 16) = u32x4{p[0], p[1], p[2], p[3]};
    }
    const float d0 = base - 48.0f * kStep, d1 = base - 49.0f * kStep;
    *(u32x4*)(myrow + 6 * 16) =
        u32x4{pack2(__expf(kCoeff * d0 * d0), __expf(kCoeff * d1 * d1)), 0u, 0u, 0u};
    *(u32x4*)(myrow + 7 * 16) =
        u32x4{pack2(sa.x, sa.y), pack2(sa.z, sa.w), pack2(sb.x, sb.y), pack2(sb.z, sb.w)};
    *(u32x4*)(myrow + 8 * 16) =
        u32x4{pack2(sc4.x, sc4.y), pack2(sc4.z, sc4.w), pack2(sd4.x, sd4.y), pack2(sd4.z, sd4.w)};
    *(u32x4*)(myrow + 9 * 16) =
        u32x4{pack2(da.x, da.y), pack2(da.z, da.w), pack2(db.x, db.y), pack2(db.z, db.w)};
    *(u32x4*)(myrow + 10 * 16) =
        u32x4{pack2(dc4.x, dc4.y), pack2(dc4.z, dc4.w), pack2(dd4.x, dd4.y), pack2(dd4.z, dd4.w)};
    *(u32x4*)(myrow + 11 * 16) = u32x4{0u, 0u, 0u, 0u};
  }

  const float v1f[12] = {va.x, va.y, va.z, va.w, vb.x, vb.y, vb.z, vb.w,
                         vc.x, vc.y, vc.z, vc.w};

  // ---- hoist ef fragments (B-operand: lane holds ef[e=g*16+lc][k=(ks*4+lq)*8+j]) ----
  half8 eff[4][3];
#pragma unroll
  for (int g = 0; g < 4; ++g) {
    const char* rp = ub + (wv * 64 + g * 16 + lc) * kRowB;
#pragma unroll
    for (int ks = 0; ks < 3; ++ks)
      eff[g][ks] = *(const half8*)(rp + (ks * 4 + lq) * 16);
  }

  // ---- stash sh/v1 as f32 into chunks 8..11 (ef chunks 8..11 now dead) ----
  *(f32x4*)(myrow + 8 * 16) = f32x4{sh0, sh1, sh2, v1f[0]};
  *(f32x4*)(myrow + 9 * 16) = f32x4{v1f[1], v1f[2], v1f[3], v1f[4]};
  *(f32x4*)(myrow + 10 * 16) = f32x4{v1f[5], v1f[6], v1f[7], v1f[8]};
  *(f32x4*)(myrow + 11 * 16) = f32x4{v1f[9], v1f[10], v1f[11], 0.0f};

  // ---- MFMA-1: h[n][e] = relu(b1[n] + sum_k W1p[k][n] ef[e][k]) ----
#pragma unroll
  for (int nt = 0; nt < 4; ++nt) {
    const half8 a0 = *(const half8*)(img1 + ((0 + lq) * 64 + nt * 16 + lc) * 16);
    const half8 a1 = *(const half8*)(img1 + ((4 + lq) * 64 + nt * 16 + lc) * 16);
    const half8 a2 = *(const half8*)(img1 + ((8 + lq) * 64 + nt * 16 + lc) * 16);
    const f32x4 bias = *(const f32x4*)(b1 + nt * 16 + lq * 4);
#pragma unroll
    for (int g = 0; g < 4; ++g) {
      f32x4 acc = bias;
      acc = __builtin_amdgcn_mfma_f32_16x16x32_f16(a0, eff[g][0], acc, 0, 0, 0);
      acc = __builtin_amdgcn_mfma_f32_16x16x32_f16(a1, eff[g][1], acc, 0, 0, 0);
      acc = __builtin_amdgcn_mfma_f32_16x16x32_f16(a2, eff[g][2], acc, 0, 0, 0);
      const unsigned p0 = pack2(fmaxf(acc[0], 0.0f), fmaxf(acc[1], 0.0f));
      const unsigned p1 = pack2(fmaxf(acc[2], 0.0f), fmaxf(acc[3], 0.0f));
      const int row = wv * 64 + g * 16 + lc;
      // n = nt*16 + lq*4 + r -> byte 2n = nt*32 + lq*8
      *(u32x2*)(ub + row * kRowB + nt * 32 + lq * 8) = u32x2{p0, p1};
    }
  }

  // ---- load h fragments (B-operand: lane holds h[k][e=g*16+lc]) ----
  half8 hf[4][2];
#pragma unroll
  for (int g = 0; g < 4; ++g) {
    const char* rp = ub + (wv * 64 + g * 16 + lc) * kRowB;
    hf[g][0] = *(const half8*)(rp + (0 + lq) * 16);
    hf[g][1] = *(const half8*)(rp + (4 + lq) * 16);
  }

  // ---- hoist per-edge sh / v1 (lane owns edge lc of each group) ----
  float shv[4][3], v1h[4][3];
#pragma unroll
  for (int g = 0; g < 4; ++g) {
    const char* rp = ub + (wv * 64 + g * 16 + lc) * kRowB;
#pragma unroll
    for (int c = 0; c < 3; ++c) {
      shv[g][c] = *(const float*)(rp + 128 + 4 * c);
      v1h[g][c] = *(const float*)(rp + 140 + 12 * lq + 4 * c);
    }
  }

  // ---- o0[20] as f32 into chunks 0..4 (h region dead now that hf is in regs) ----
  {
    const float t0 = (v1f[0] * sh0 + v1f[1] * sh1 + v1f[2] * sh2) * kInvSqrt3;
    const float t1 = (v1f[3] * sh0 + v1f[4] * sh1 + v1f[5] * sh2) * kInvSqrt3;
    const float t2 = (v1f[6] * sh0 + v1f[7] * sh1 + v1f[8] * sh2) * kInvSqrt3;
    const float t3 = (v1f[9] * sh0 + v1f[10] * sh1 + v1f[11] * sh2) * kInvSqrt3;
    *(f32x4*)(myrow + 0) = f32x4{sa.x, sa.y, sa.z, sa.w};
    *(f32x4*)(myrow + 16) = f32x4{sb.x, sb.y, sb.z, sb.w};
    *(f32x4*)(myrow + 32) = f32x4{sc4.x, sc4.y, sc4.z, sc4.w};
    *(f32x4*)(myrow + 48) = f32x4{sd4.x, sd4.y, sd4.z, sd4.w};
    *(f32x4*)(myrow + 64) = f32x4{t0, t1, t2, t3};
  }

  // ---- MFMA-2 + fused contraction. D[n][e]: lane owns edge lc, n = 16nt+4lq+r ----
  float macc0[4][4] = {};
  float macc1[4][4][3] = {};

#pragma unroll 5
  for (int nt = 0; nt < 20; ++nt) {
    const half8 w0 = *(const half8*)(img2 + ((0 + lq) * 400 + nt * 16 + lc) * 16);
    const half8 w1 = *(const half8*)(img2 + ((4 + lq) * 400 + nt * 16 + lc) * 16);
    const f32x4 bias = *(const f32x4*)(b2 + nt * 16 + lq * 4);
#pragma unroll
    for (int g = 0; g < 4; ++g) {
      f32x4 acc = bias;
      acc = __builtin_amdgcn_mfma_f32_16x16x32_f16(w0, hf[g][0], acc, 0, 0, 0);
      acc = __builtin_amdgcn_mfma_f32_16x16x32_f16(w1, hf[g][1], acc, 0, 0, 0);
      const char* rp0 = ub + (wv * 64 + g * 16 + lc) * kRowB;
      const float o0v = *(const float*)(rp0 + 4 * nt);   // broadcast (4 lanes/addr)
#pragma unroll
      for (int r = 0; r < 4; ++r) macc0[g][r] = fmaf(o0v, acc[r], macc0[g][r]);
    }
  }
#pragma unroll
  for (int nt = 20; nt < 24; ++nt) {
    const half8 w0 = *(const half8*)(img2 + ((0 + lq) * 400 + nt * 16 + lc) * 16);
    const half8 w1 = *(const half8*)(img2 + ((4 + lq) * 400 + nt * 16 + lc) * 16);
    const f32x4 bias = *(const f32x4*)(b2 + nt * 16 + lq * 4);
#pragma unroll
    for (int g = 0; g < 4; ++g) {
      f32x4 acc = bias;
      acc = __builtin_amdgcn_mfma_f32_16x16x32_f16(w0, hf[g][0], acc, 0, 0, 0);
      acc = __builtin_amdgcn_mfma_f32_16x16x32_f16(w1, hf[g][1], acc, 0, 0, 0);
      const char* rp0 = ub + (wv * 64 + g * 16 + lc) * kRowB;
      // i = 4*(nt-20) + lq, o = r; o1[i] = ss[i] * sh; ss[i] = o0[i] (f32)
      const float ssv = *(const float*)(rp0 + 16 * (nt - 20) + 4 * lq);
      float pc[3];
#pragma unroll
      for (int c = 0; c < 3; ++c) pc[c] = ssv * shv[g][c];
#pragma unroll
      for (int r = 0; r < 4; ++r)
#pragma unroll
        for (int c = 0; c < 3; ++c)
          macc1[g][r][c] = fmaf(pc[c], acc[r], macc1[g][r][c]);
    }
  }
  {  // nt = 24: i = 16 + lq, o1 row = in_1o
    const int nt = 24;
    const half8 w0 = *(const half8*)(img2 + ((0 + lq) * 400 + nt * 16 + lc) * 16);
    const half8 w1 = *(const half8*)(img2 + ((4 + lq) * 400 + nt * 16 + lc) * 16);
    const f32x4 bias = *(const f32x4*)(b2 + nt * 16 + lq * 4);
#pragma unroll
    for (int g = 0; g < 4; ++g) {
      f32x4 acc = bias;
      acc = __builtin_amdgcn_mfma_f32_16x16x32_f16(w0, hf[g][0], acc, 0, 0, 0);
      acc = __builtin_amdgcn_mfma_f32_16x16x32_f16(w1, hf[g][1], acc, 0, 0, 0);
#pragma unroll
      for (int r = 0; r < 4; ++r)
#pragma unroll
        for (int c = 0; c < 3; ++c)
          macc1[g][r][c] = fmaf(v1h[g][c], acc[r], macc1[g][r][c]);
    }
  }

  // ---- finish msg1 (reduce i-partition across lq groups), scale, write msg rows ----
#pragma unroll
  for (int g = 0; g < 4; ++g)
#pragma unroll
    for (int r = 0; r < 4; ++r)
#pragma unroll
      for (int c = 0; c < 3; ++c) {
        float x = macc1[g][r][c];
        x += __shfl_xor(x, 16);
        x += __shfl_xor(x, 32);
        macc1[g][r][c] = x * kInvSqrt20;
      }
#pragma unroll
  for (int g = 0; g < 4; ++g) {
    char* rp = ub + (wv * 64 + g * 16 + lc) * kRowB;
    *(f32x4*)(rp + lq * 16) =
        f32x4{macc0[g][0] * kInvSqrt20, macc0[g][1] * kInvSqrt20,
              macc0[g][2] * kInvSqrt20, macc0[g][3] * kInvSqrt20};
    f32x4 m1;
    if (lq == 1)
      m1 = f32x4{macc1[g][0][0], macc1[g][0][1], macc1[g][0][2], macc1[g][1][0]};
    else if (lq == 2)
      m1 = f32x4{macc1[g][1][1], macc1[g][1][2], macc1[g][2][0], macc1[g][2][1]};
    else
      m1 = f32x4{macc1[g][2][2], macc1[g][3][0], macc1[g][3][1], macc1[g][3][2]};
    if (lq != 0) *(f32x4*)(rp + 48 + lq * 16) = m1;
  }

  // ---- read back own msg, segmented wave reduction, one atomic per segment head ----
  float msg[28];
  {
    const char* rp = ub + tid * kRowB;
#pragma unroll
    for (int c = 0; c < 7; ++c) {
      const f32x4 v = *(const f32x4*)(rp + c * 16);
      msg[c * 4 + 0] = v[0];
      msg[c * 4 + 1] = v[1];
      msg[c * 4 + 2] = v[2];
      msg[c * 4 + 3] = v[3];
    }
  }
#pragma unroll
  for (int d = 1; d < 64; d <<= 1) {
    const int od = __shfl_down(dstv, d);
    const bool same = (lane + d < 64) && (od == dstv);
#pragma unroll
    for (int j = 0; j < 28; j++) {
      const float ov = __shfl_down(msg[j], d);
      if (same) msg[j] += ov;
    }
  }
  const int pd = __shfl_up(dstv, 1);
  if ((lane == 0 || pd != dstv) && dstv >= 0) {
    // pre-normalize: agg was seeded with node_attr; adding msg/cnt completes
    // out = node_attr + (segment-sum)/cnt without a finalize pass.
    const float rc = 1.0f / fmaxf((float)cnt[dstv], 1.0f);
    float* ap = agg + (size_t)dstv * kAttr;
#pragma unroll
    for (int j = 0; j < 28; j++) atomicAdd(ap + j, msg[j] * rc);
  }
}

extern "C" void kernel_launch(void* const* d_in, const int* in_sizes, int n_in,
                              void* d_out, int out_size, void* d_ws, size_t ws_size,
                              hipStream_t stream) {
  const float* node_attr = (const float*)d_in[0];
  const float* pos = (const float*)d_in[1];
  const float* W1 = (const float*)d_in[2];
  const float* b1 = (const float*)d_in[3];
  const float* W2 = (const float*)d_in[4];
  const float* b2 = (const float*)d_in[5];
  const int* edge_index = (const int*)d_in[6];

  const int N = in_sizes[0] / kAttr;
  const int E = in_sizes[6] / 2;

  // ws layout: [img1][img2][cnt N][node_start N][rank E][sedge E int2] ~4.0MB
  char* wsc = (char*)d_ws;
  unsigned short* img1 = (unsigned short*)wsc;
  unsigned short* img2 = (unsigned short*)(wsc + kImg1Bytes);
  int* cnt = (int*)(wsc + kImg1Bytes + kImg2Bytes);
  int* node_start = cnt + N;
  int* rank = node_start + N;
  int2* sedge = (int2*)(rank + E);

  float* agg = (float*)d_out;
  const int aggN4 = out_size / 4;
  const int eblocks = (E + 255) / 256;

  // 5 dispatches, all plain (r9: no grid.sync; r8: no mega-fuse; r12: no
  // finalize; r13: one atomic pass, rank-addressed scatter).
  init_kernel<<<512, 256, 0, stream>>>(W1, W2, node_attr, img1, img2, cnt, agg,
                                       aggN4, N);
  hist_rank_kernel<<<eblocks, 256, 0, stream>>>(edge_index, cnt, rank, E);
  scan_kernel<<<1, 256, 0, stream>>>(cnt, node_start, N);
  scatter_kernel<<<eblocks, 256, 0, stream>>>(edge_index, node_start, rank,
                                              sedge, E);
  tfn_mfma_kernel<<<eblocks, 256, 0, stream>>>(
      node_attr, pos, b1, b2, (const char*)img1, (const char*)img2,
      sedge, cnt, agg, E);
}

// Round 17
// 95.247 us; speedup vs baseline: 4.3241x; 1.1285x over previous
//
#include <hip/hip_runtime.h>
#include <math.h>

typedef _Float16 half8 __attribute__((ext_vector_type(8)));
typedef float f32x4 __attribute__((ext_vector_type(4)));
typedef unsigned int u32x4 __attribute__((ext_vector_type(4)));
typedef unsigned int u32x2 __attribute__((ext_vector_type(2)));

namespace {
constexpr int kNS = 16;
constexpr int kNV = 4;
constexpr int kNG = 50;
constexpr int kHID = 64;
constexpr int kAttr = 28;                 // NS + 3*NV
constexpr int kWNUM = 400;
constexpr float kStep = 5.0f / 49.0f;
constexpr float kCoeff = -0.5f / (kStep * kStep);
constexpr float kSqrt3 = 1.7320508075688772f;
constexpr float kInvSqrt3 = 0.57735026918962576f;
constexpr float kInvSqrt20 = 0.22360679774997896f;
// Row = 208 B (13 granules): 52 words == 20 mod 32 -> 16 rows spread over 8
// bank-offset classes (2 lanes/bank = free). No XOR swizzle (r3 lesson).
constexpr int kRowB = 208;
constexpr int kImg1Bytes = 96 * 64 * 2;   // 12288
constexpr int kImg2Bytes = 64 * 400 * 2;  // 51200
}  // namespace

// f16 end-to-end (r6-r16: absmax 0.016-0.09 vs threshold 0.101).
// (_Float16) cast = hardware v_cvt_f16_f32 RNE (r5: hip bf16 helpers truncate).
// r14/r15 lessons: no memcpy/address-cast of register-array elements; no full
// unroll of MFMA-2 (live-range explosion -> scratch). r13 body is the proven
// form. r17: main-kernel atomics (420K RMW ~= 32us at 13G/s, WRITE_SIZE 35MB
// of RMW lines) replaced by collision-free head-slot STORES + finalize sum.
__device__ __forceinline__ unsigned short f2h(float x) {
  _Float16 h = (_Float16)x;
  unsigned short r;
  __builtin_memcpy(&r, &h, 2);
  return r;
}
__device__ __forceinline__ unsigned pack2(float lo, float hi) {
  return (unsigned)f2h(lo) | ((unsigned)f2h(hi) << 16);
}

// ---------- A: fused init (agg=node_attr is gone; zero cnt+part; f16 imgs) ---
__global__ __launch_bounds__(256) void init_kernel(
    const float* __restrict__ W1, const float* __restrict__ W2,
    unsigned short* __restrict__ img1, unsigned short* __restrict__ img2,
    int* __restrict__ cnt, float* __restrict__ part, int partN4, int N) {
  const int gtid = blockIdx.x * 256 + threadIdx.x;
  const int gsz = gridDim.x * 256;
  f32x4* p4 = (f32x4*)part;
  for (int i = gtid; i < partN4; i += gsz) p4[i] = f32x4{0.f, 0.f, 0.f, 0.f};
  for (int i = gtid; i < N; i += gsz) cnt[i] = 0;
  // img layout: element (k, n) at byte ((k>>3)*W + n)*16 + 2*(k&7)
  for (int i = gtid; i < 96 * 64 + 64 * 400; i += gsz) {
    if (i < 96 * 64) {
      const int m = i >> 6, n = i & 63;
      float v = 0.0f;
      if (m < 50) v = W1[m * 64 + n];                        // gaussian rows
      else if (m >= 56 && m < 88) v = W1[(m - 6) * 64 + n];  // ss, ds rows
      img1[((m >> 3) * 64 + n) * 8 + (m & 7)] = f2h(v);
    } else {
      const int j = i - 96 * 64;
      const int m = j / 400, n = j % 400;
      img2[((m >> 3) * 400 + n) * 8 + (m & 7)] = f2h(W2[m * 400 + n]);
    }
  }
}

// ---------- B: histogram of dst + per-edge rank (the ONLY atomic pass) -------
__global__ __launch_bounds__(256) void hist_rank_kernel(
    const int* __restrict__ edge_index, int* __restrict__ cnt,
    int* __restrict__ rank, int E) {
  const int e = blockIdx.x * blockDim.x + threadIdx.x;
  if (e >= E) return;
  rank[e] = atomicAdd(cnt + edge_index[E + e], 1);
}

// ---------- C: exclusive scan cnt -> node_start (single block, wave-scan) ----
__global__ __launch_bounds__(256) void scan_kernel(
    const int* __restrict__ cnt, int* __restrict__ node_start, int N) {
  __shared__ int wsum[4];
  const int tid = threadIdx.x;
  const int lane = tid & 63;
  const int wv = tid >> 6;
  const int n4 = (N + 3) >> 2;
  const int tiles = (n4 + 255) / 256;
  int running = 0;
  for (int k = 0; k < tiles; ++k) {
    const int i4 = k * 256 + tid;
    int4 v = {0, 0, 0, 0};
    const int base = i4 * 4;
    if (i4 < n4) {
      if (base + 3 < N) {
        v = *(const int4*)(cnt + base);
      } else {
        if (base + 0 < N) v.x = cnt[base + 0];
        if (base + 1 < N) v.y = cnt[base + 1];
        if (base + 2 < N) v.z = cnt[base + 2];
      }
    }
    const int e1 = v.x, e2 = v.x + v.y, e3 = e2 + v.z, s4 = e3 + v.w;
    int incl = s4;
#pragma unroll
    for (int d = 1; d < 64; d <<= 1) {
      const int y = __shfl_up(incl, d);
      if (lane >= d) incl += y;
    }
    if (lane == 63) wsum[wv] = incl;
    __syncthreads();
    int wbase = 0;
#pragma unroll
    for (int w = 0; w < 4; ++w) wbase += (w < wv) ? wsum[w] : 0;
    const int block_total = wsum[0] + wsum[1] + wsum[2] + wsum[3];
    const int tbase = running + wbase + (incl - s4);
    if (i4 < n4) {
      if (base + 0 < N) node_start[base + 0] = tbase;
      if (base + 1 < N) node_start[base + 1] = tbase + e1;
      if (base + 2 < N) node_start[base + 2] = tbase + e2;
      if (base + 3 < N) node_start[base + 3] = tbase + e3;
    }
    running += block_total;
    __syncthreads();  // wsum reused next tile
  }
}

// ---------- D: scatter (ATOMIC-FREE: slot = node_start[d] + rank[e]) ---------
__global__ __launch_bounds__(256) void scatter_kernel(
    const int* __restrict__ edge_index, const int* __restrict__ node_start,
    const int* __restrict__ rank, int2* __restrict__ sedge, int E) {
  const int e = blockIdx.x * blockDim.x + threadIdx.x;
  if (e >= E) return;
  const int s = edge_index[e];
  const int d = edge_index[E + e];
  sedge[node_start[d] + rank[e]] = int2{s, d};
}

// ---------- E: main MFMA edge kernel (r13 body; tail = head-slot stores) -----
// Per wave: 64 edges (4 groups of 16). All LDS traffic is wave-local.
// ub row (208B) timeline: ef(96 f16, chunks 0..11) -> h(chunks 0..7) +
// sh/v1 stash(chunks 8..11) -> o0 f32(chunks 0..4, after hf hoist) ->
// msg(28 f32, chunks 0..6). LDS 53248 B => 3 blocks/CU.
// r17 tail: segment heads STORE partials to unique slots (no atomics):
//   non-lane0 head at sorted pos t => t == node_start[dst] => slot = dst
//   lane0 head (t % 64 == 0)       => slot = N + t/64
__global__ __launch_bounds__(256, 3) void tfn_mfma_kernel(
    const float* __restrict__ node_attr, const float* __restrict__ pos,
    const float* __restrict__ b1, const float* __restrict__ b2,
    const char* __restrict__ img1, const char* __restrict__ img2,
    const int2* __restrict__ sedge, float* __restrict__ part, int N, int E) {
  __shared__ __align__(16) char ub[256 * kRowB];   // 53248 B (3 blocks/CU)

  const int tid = threadIdx.x;
  const int t = blockIdx.x * 256 + tid;
  const int lane = tid & 63;
  const int wv = tid >> 6;
  const int lc = lane & 15, lq = lane >> 4;

  const bool valid = (t < E);
  int src = 0, dstv = -1;
  if (valid) {
    const int2 se = sedge[t];
    src = se.x;
    dstv = se.y;
  }
  const int dn = valid ? dstv : 0;

  // ---- geometry ----
  const float psx = pos[src * 3 + 0], psy = pos[src * 3 + 1], psz = pos[src * 3 + 2];
  const float pdx = pos[dn * 3 + 0], pdy = pos[dn * 3 + 1], pdz = pos[dn * 3 + 2];
  const float vx = pdx - psx, vy = pdy - psy, vz = pdz - psz;
  const float dist = sqrtf(vx * vx + vy * vy + vz * vz);
  const float rinv = 1.0f / fmaxf(dist, 1e-8f);
  const float sh0 = kSqrt3 * (vy * rinv);
  const float sh1 = kSqrt3 * (vz * rinv);
  const float sh2 = kSqrt3 * (vx * rinv);

  const float* nas = node_attr + (size_t)src * kAttr;
  const float* nad = node_attr + (size_t)dn * kAttr;
  const float4 sa = *(const float4*)(nas + 0);
  const float4 sb = *(const float4*)(nas + 4);
  const float4 sc4 = *(const float4*)(nas + 8);
  const float4 sd4 = *(const float4*)(nas + 12);
  const float4 va = *(const float4*)(nas + 16);
  const float4 vb = *(const float4*)(nas + 20);
  const float4 vc = *(const float4*)(nas + 24);
  const float4 da = *(const float4*)(nad + 0);
  const float4 db = *(const float4*)(nad + 4);
  const float4 dc4 = *(const float4*)(nad + 8);
  const float4 dd4 = *(const float4*)(nad + 12);

  char* myrow = ub + tid * kRowB;

  // ---- write ef row (96 f16): [gauss50 | 0x6 | ss16 | ds16 | 0x8] ----
  {
    const float base = dist + 1e-6f;
#pragma unroll
    for (int c = 0; c < 6; ++c) {
      unsigned p[4];
#pragma unroll
      for (int u = 0; u < 4; ++u) {
        const int k = c * 8 + u * 2;
        const float d0 = base - (float)k * kStep;
        const float d1 = base - (float)(k + 1) * kStep;
        p[u] = pack2(__expf(kCoeff * d0 * d0), __expf(kCoeff * d1 * d1));
      }
      *(u32x4*)(myrow + c * 16) = u32x4{p[0], p[1], p[2], p[3]};
    }
    const float d0 = base - 48.0f * kStep, d1 = base - 49.0f * kStep;
    *(u32x4*)(myrow + 6 * 16) =
        u32x4{pack2(__expf(kCoeff * d0 * d0), __expf(kCoeff * d1 * d1)), 0u, 0u, 0u};
    *(u32x4*)(myrow + 7 * 16) =
        u32x4{pack2(sa.x, sa.y), pack2(sa.z, sa.w), pack2(sb.x, sb.y), pack2(sb.z, sb.w)};
    *(u32x4*)(myrow + 8 * 16) =
        u32x4{pack2(sc4.x, sc4.y), pack2(sc4.z, sc4.w), pack2(sd4.x, sd4.y), pack2(sd4.z, sd4.w)};
    *(u32x4*)(myrow + 9 * 16) =
        u32x4{pack2(da.x, da.y), pack2(da.z, da.w), pack2(db.x, db.y), pack2(db.z, db.w)};
    *(u32x4*)(myrow + 10 * 16) =
        u32x4{pack2(dc4.x, dc4.y), pack2(dc4.z, dc4.w), pack2(dd4.x, dd4.y), pack2(dd4.z, dd4.w)};
    *(u32x4*)(myrow + 11 * 16) = u32x4{0u, 0u, 0u, 0u};
  }

  const float v1f[12] = {va.x, va.y, va.z, va.w, vb.x, vb.y, vb.z, vb.w,
                         vc.x, vc.y, vc.z, vc.w};

  // ---- hoist ef fragments (B-operand: lane holds ef[e=g*16+lc][k=(ks*4+lq)*8+j]) ----
  half8 eff[4][3];
#pragma unroll
  for (int g = 0; g < 4; ++g) {
    const char* rp = ub + (wv * 64 + g * 16 + lc) * kRowB;
#pragma unroll
    for (int ks = 0; ks < 3; ++ks)
      eff[g][ks] = *(const half8*)(rp + (ks * 4 + lq) * 16);
  }

  // ---- stash sh/v1 as f32 into chunks 8..11 (ef chunks 8..11 now dead) ----
  *(f32x4*)(myrow + 8 * 16) = f32x4{sh0, sh1, sh2, v1f[0]};
  *(f32x4*)(myrow + 9 * 16) = f32x4{v1f[1], v1f[2], v1f[3], v1f[4]};
  *(f32x4*)(myrow + 10 * 16) = f32x4{v1f[5], v1f[6], v1f[7], v1f[8]};
  *(f32x4*)(myrow + 11 * 16) = f32x4{v1f[9], v1f[10], v1f[11], 0.0f};

  // ---- MFMA-1: h[n][e] = relu(b1[n] + sum_k W1p[k][n] ef[e][k]) ----
#pragma unroll
  for (int nt = 0; nt < 4; ++nt) {
    const half8 a0 = *(const half8*)(img1 + ((0 + lq) * 64 + nt * 16 + lc) * 16);
    const half8 a1 = *(const half8*)(img1 + ((4 + lq) * 64 + nt * 16 + lc) * 16);
    const half8 a2 = *(const half8*)(img1 + ((8 + lq) * 64 + nt * 16 + lc) * 16);
    const f32x4 bias = *(const f32x4*)(b1 + nt * 16 + lq * 4);
#pragma unroll
    for (int g = 0; g < 4; ++g) {
      f32x4 acc = bias;
      acc = __builtin_amdgcn_mfma_f32_16x16x32_f16(a0, eff[g][0], acc, 0, 0, 0);
      acc = __builtin_amdgcn_mfma_f32_16x16x32_f16(a1, eff[g][1], acc, 0, 0, 0);
      acc = __builtin_amdgcn_mfma_f32_16x16x32_f16(a2, eff[g][2], acc, 0, 0, 0);
      const unsigned p0 = pack2(fmaxf(acc[0], 0.0f), fmaxf(acc[1], 0.0f));
      const unsigned p1 = pack2(fmaxf(acc[2], 0.0f), fmaxf(acc[3], 0.0f));
      const int row = wv * 64 + g * 16 + lc;
      // n = nt*16 + lq*4 + r -> byte 2n = nt*32 + lq*8
      *(u32x2*)(ub + row * kRowB + nt * 32 + lq * 8) = u32x2{p0, p1};
    }
  }

  // ---- load h fragments (B-operand: lane holds h[k][e=g*16+lc]) ----
  half8 hf[4][2];
#pragma unroll
  for (int g = 0; g < 4; ++g) {
    const char* rp = ub + (wv * 64 + g * 16 + lc) * kRowB;
    hf[g][0] = *(const half8*)(rp + (0 + lq) * 16);
    hf[g][1] = *(const half8*)(rp + (4 + lq) * 16);
  }

  // ---- hoist per-edge sh / v1 (lane owns edge lc of each group) ----
  float shv[4][3], v1h[4][3];
#pragma unroll
  for (int g = 0; g < 4; ++g) {
    const char* rp = ub + (wv * 64 + g * 16 + lc) * kRowB;
#pragma unroll
    for (int c = 0; c < 3; ++c) {
      shv[g][c] = *(const float*)(rp + 128 + 4 * c);
      v1h[g][c] = *(const float*)(rp + 140 + 12 * lq + 4 * c);
    }
  }

  // ---- o0[20] as f32 into chunks 0..4 (h region dead now that hf is in regs) ----
  {
    const float t0 = (v1f[0] * sh0 + v1f[1] * sh1 + v1f[2] * sh2) * kInvSqrt3;
    const float t1 = (v1f[3] * sh0 + v1f[4] * sh1 + v1f[5] * sh2) * kInvSqrt3;
    const float t2 = (v1f[6] * sh0 + v1f[7] * sh1 + v1f[8] * sh2) * kInvSqrt3;
    const float t3 = (v1f[9] * sh0 + v1f[10] * sh1 + v1f[11] * sh2) * kInvSqrt3;
    *(f32x4*)(myrow + 0) = f32x4{sa.x, sa.y, sa.z, sa.w};
    *(f32x4*)(myrow + 16) = f32x4{sb.x, sb.y, sb.z, sb.w};
    *(f32x4*)(myrow + 32) = f32x4{sc4.x, sc4.y, sc4.z, sc4.w};
    *(f32x4*)(myrow + 48) = f32x4{sd4.x, sd4.y, sd4.z, sd4.w};
    *(f32x4*)(myrow + 64) = f32x4{t0, t1, t2, t3};
  }

  // ---- MFMA-2 + fused contraction. D[n][e]: lane owns edge lc, n = 16nt+4lq+r ----
  float macc0[4][4] = {};
  float macc1[4][4][3] = {};

#pragma unroll 5
  for (int nt = 0; nt < 20; ++nt) {
    const half8 w0 = *(const half8*)(img2 + ((0 + lq) * 400 + nt * 16 + lc) * 16);
    const half8 w1 = *(const half8*)(img2 + ((4 + lq) * 400 + nt * 16 + lc) * 16);
    const f32x4 bias = *(const f32x4*)(b2 + nt * 16 + lq * 4);
#pragma unroll
    for (int g = 0; g < 4; ++g) {
      f32x4 acc = bias;
      acc = __builtin_amdgcn_mfma_f32_16x16x32_f16(w0, hf[g][0], acc, 0, 0, 0);
      acc = __builtin_amdgcn_mfma_f32_16x16x32_f16(w1, hf[g][1], acc, 0, 0, 0);
      const char* rp0 = ub + (wv * 64 + g * 16 + lc) * kRowB;
      const float o0v = *(const float*)(rp0 + 4 * nt);   // broadcast (4 lanes/addr)
#pragma unroll
      for (int r = 0; r < 4; ++r) macc0[g][r] = fmaf(o0v, acc[r], macc0[g][r]);
    }
  }
#pragma unroll
  for (int nt = 20; nt < 24; ++nt) {
    const half8 w0 = *(const half8*)(img2 + ((0 + lq) * 400 + nt * 16 + lc) * 16);
    const half8 w1 = *(const half8*)(img2 + ((4 + lq) * 400 + nt * 16 + lc) * 16);
    const f32x4 bias = *(const f32x4*)(b2 + nt * 16 + lq * 4);
#pragma unroll
    for (int g = 0; g < 4; ++g) {
      f32x4 acc = bias;
      acc = __builtin_amdgcn_mfma_f32_16x16x32_f16(w0, hf[g][0], acc, 0, 0, 0);
      acc = __builtin_amdgcn_mfma_f32_16x16x32_f16(w1, hf[g][1], acc, 0, 0, 0);
      const char* rp0 = ub + (wv * 64 + g * 16 + lc) * kRowB;
      // i = 4*(nt-20) + lq, o = r; o1[i] = ss[i] * sh; ss[i] = o0[i] (f32)
      const float ssv = *(const float*)(rp0 + 16 * (nt - 20) + 4 * lq);
      float pc[3];
#pragma unroll
      for (int c = 0; c < 3; ++c) pc[c] = ssv * shv[g][c];
#pragma unroll
      for (int r = 0; r < 4; ++r)
#pragma unroll
        for (int c = 0; c < 3; ++c)
          macc1[g][r][c] = fmaf(pc[c], acc[r], macc1[g][r][c]);
    }
  }
  {  // nt = 24: i = 16 + lq, o1 row = in_1o
    const int nt = 24;
    const half8 w0 = *(const half8*)(img2 + ((0 + lq) * 400 + nt * 16 + lc) * 16);
    const half8 w1 = *(const half8*)(img2 + ((4 + lq) * 400 + nt * 16 + lc) * 16);
    const f32x4 bias = *(const f32x4*)(b2 + nt * 16 + lq * 4);
#pragma unroll
    for (int g = 0; g < 4; ++g) {
      f32x4 acc = bias;
      acc = __builtin_amdgcn_mfma_f32_16x16x32_f16(w0, hf[g][0], acc, 0, 0, 0);
      acc = __builtin_amdgcn_mfma_f32_16x16x32_f16(w1, hf[g][1], acc, 0, 0, 0);
#pragma unroll
      for (int r = 0; r < 4; ++r)
#pragma unroll
        for (int c = 0; c < 3; ++c)
          macc1[g][r][c] = fmaf(v1h[g][c], acc[r], macc1[g][r][c]);
    }
  }

  // ---- finish msg1 (reduce i-partition across lq groups), scale, write msg rows ----
#pragma unroll
  for (int g = 0; g < 4; ++g)
#pragma unroll
    for (int r = 0; r < 4; ++r)
#pragma unroll
      for (int c = 0; c < 3; ++c) {
        float x = macc1[g][r][c];
        x += __shfl_xor(x, 16);
        x += __shfl_xor(x, 32);
        macc1[g][r][c] = x * kInvSqrt20;
      }
#pragma unroll
  for (int g = 0; g < 4; ++g) {
    char* rp = ub + (wv * 64 + g * 16 + lc) * kRowB;
    *(f32x4*)(rp + lq * 16) =
        f32x4{macc0[g][0] * kInvSqrt20, macc0[g][1] * kInvSqrt20,
              macc0[g][2] * kInvSqrt20, macc0[g][3] * kInvSqrt20};
    f32x4 m1;
    if (lq == 1)
      m1 = f32x4{macc1[g][0][0], macc1[g][0][1], macc1[g][0][2], macc1[g][1][0]};
    else if (lq == 2)
      m1 = f32x4{macc1[g][1][1], macc1[g][1][2], macc1[g][2][0], macc1[g][2][1]};
    else
      m1 = f32x4{macc1[g][2][2], macc1[g][3][0], macc1[g][3][1], macc1[g][3][2]};
    if (lq != 0) *(f32x4*)(rp + 48 + lq * 16) = m1;
  }

  // ---- read back own msg, segmented wave reduction, head-slot STORES ----
  float msg[28];
  {
    const char* rp = ub + tid * kRowB;
#pragma unroll
    for (int c = 0; c < 7; ++c) {
      const f32x4 v = *(const f32x4*)(rp + c * 16);
      msg[c * 4 + 0] = v[0];
      msg[c * 4 + 1] = v[1];
      msg[c * 4 + 2] = v[2];
      msg[c * 4 + 3] = v[3];
    }
  }
#pragma unroll
  for (int d = 1; d < 64; d <<= 1) {
    const int od = __shfl_down(dstv, d);
    const bool same = (lane + d < 64) && (od == dstv);
#pragma unroll
    for (int j = 0; j < 28; j++) {
      const float ov = __shfl_down(msg[j], d);
      if (same) msg[j] += ov;
    }
  }
  const int pd = __shfl_up(dstv, 1);
  if ((lane == 0 || pd != dstv) && dstv >= 0) {
    // unique head slot: lane0 head -> N + t/64 (t % 64 == 0); other heads are
    // first-of-node (t == node_start[dst]) -> slot dst. Plain stores, no RMW.
    const int slot = (lane == 0) ? (N + (t >> 6)) : dstv;
    float* pp = part + (size_t)slot * kAttr;
#pragma unroll
    for (int c = 0; c < 7; ++c)
      *(f32x4*)(pp + c * 4) =
          f32x4{msg[c * 4 + 0], msg[c * 4 + 1], msg[c * 4 + 2], msg[c * 4 + 3]};
  }
}

// ---------- F: finalize — sum 1-2 head slots, normalize, add node_attr ------
__global__ __launch_bounds__(256) void tfn_finalize_kernel(
    const float* __restrict__ node_attr, const int* __restrict__ cnt,
    const int* __restrict__ node_start, const float* __restrict__ part,
    float* __restrict__ out, int N, int total) {
  const int i = blockIdx.x * blockDim.x + threadIdx.x;
  if (i >= total) return;
  const int n = i / kAttr;
  const int j = i - n * kAttr;
  const int c = cnt[n];
  float s = part[(size_t)n * kAttr + j];          // first-of-node slot (0 if unused)
  const int ns = node_start[n];
  // wave-boundary heads: multiples of 64 in [ns, ns+c)
  for (int k = (ns + 63) >> 6; k * 64 < ns + c; ++k)
    s += part[(size_t)(N + k) * kAttr + j];
  out[i] = node_attr[i] + s / fmaxf((float)c, 1.0f);
}

extern "C" void kernel_launch(void* const* d_in, const int* in_sizes, int n_in,
                              void* d_out, int out_size, void* d_ws, size_t ws_size,
                              hipStream_t stream) {
  const float* node_attr = (const float*)d_in[0];
  const float* pos = (const float*)d_in[1];
  const float* W1 = (const float*)d_in[2];
  const float* b1 = (const float*)d_in[3];
  const float* W2 = (const float*)d_in[4];
  const float* b2 = (const float*)d_in[5];
  const int* edge_index = (const int*)d_in[6];

  const int N = in_sizes[0] / kAttr;
  const int E = in_sizes[6] / 2;
  const int nslots = N + (E + 63) / 64;

  // ws layout: [img1][img2][cnt N][node_start N][rank E][sedge E int2]
  //            [part nslots*28 f32]  ~5.7MB total (ws proven >= 7.8MB, r7)
  char* wsc = (char*)d_ws;
  unsigned short* img1 = (unsigned short*)wsc;
  unsigned short* img2 = (unsigned short*)(wsc + kImg1Bytes);
  int* cnt = (int*)(wsc + kImg1Bytes + kImg2Bytes);
  int* node_start = cnt + N;
  int* rank = node_start + N;
  int2* sedge = (int2*)(rank + E);
  float* part = (float*)(sedge + E);

  const int partN4 = (nslots * kAttr) / 4;  // 28 % 4 == 0
  const int eblocks = (E + 255) / 256;
  const int total = N * kAttr;

  // 6 dispatches, all plain (r9: no grid.sync; r8: no mega-fuse; r13: one
  // atomic pass; r17: main kernel is fully atomic-free via head slots).
  init_kernel<<<512, 256, 0, stream>>>(W1, W2, img1, img2, cnt, part, partN4, N);
  hist_rank_kernel<<<eblocks, 256, 0, stream>>>(edge_index, cnt, rank, E);
  scan_kernel<<<1, 256, 0, stream>>>(cnt, node_start, N);
  scatter_kernel<<<eblocks, 256, 0, stream>>>(edge_index, node_start, rank,
                                              sedge, E);
  tfn_mfma_kernel<<<eblocks, 256, 0, stream>>>(
      node_attr, pos, b1, b2, (const char*)img1, (const char*)img2,
      sedge, part, N, E);
  tfn_finalize_kernel<<<(total + 255) / 256, 256, 0, stream>>>(
      node_attr, cnt, node_start, part, (float*)d_out, N, total);
}

// Round 19
// 94.563 us; speedup vs baseline: 4.3553x; 1.0072x over previous
//
#include <hip/hip_runtime.h>
#include <math.h>

typedef _Float16 half8 __attribute__((ext_vector_type(8)));
typedef float f32x4 __attribute__((ext_vector_type(4)));
typedef unsigned int u32x4 __attribute__((ext_vector_type(4)));
typedef unsigned int u32x2 __attribute__((ext_vector_type(2)));

namespace {
constexpr int kNS = 16;
constexpr int kNV = 4;
constexpr int kNG = 50;
constexpr int kHID = 64;
constexpr int kAttr = 28;                 // NS + 3*NV
constexpr int kWNUM = 400;
constexpr float kStep = 5.0f / 49.0f;
constexpr float kCoeff = -0.5f / (kStep * kStep);
constexpr float kSqrt3 = 1.7320508075688772f;
constexpr float kInvSqrt3 = 0.57735026918962576f;
constexpr float kInvSqrt20 = 0.22360679774997896f;
// Row = 208 B (13 granules): 52 words == 20 mod 32 -> 16 rows spread over 8
// bank-offset classes (2 lanes/bank = free). No XOR swizzle (r3 lesson).
constexpr int kRowB = 208;
constexpr int kImg1Bytes = 96 * 64 * 2;   // 12288
constexpr int kImg2Bytes = 64 * 400 * 2;  // 51200
}  // namespace

// Weights (init): RNE via (_Float16) cast = v_cvt_f16_f32 (r5: hip bf16
// helpers truncate; f16 cast is RNE).
__device__ __forceinline__ unsigned short f2h(float x) {
  _Float16 h = (_Float16)x;
  unsigned short r;
  __builtin_memcpy(&r, &h, 2);
  return r;
}
// Activations/features (main): single-instruction packed convert
// v_cvt_pkrtz_f16_f32 (1 VALU vs ~3 for cvt+cvt+pack). RTZ rounding: ~2x f16
// rounding error on these values; margin is 4x (r17 absmax 0.024 vs 0.101).
// r18 fix: builtin returns __fp16x2, a distinct type from _Float16x2 — use
// auto + memcpy of the SCALAR local (r14-safe: no array element address).
__device__ __forceinline__ unsigned pack2(float lo, float hi) {
  auto h = __builtin_amdgcn_cvt_pkrtz(lo, hi);
  unsigned r;
  __builtin_memcpy(&r, &h, 4);
  return r;
}

// ---------- A: fused init (zero cnt+part; f16 weight images) ----------
__global__ __launch_bounds__(256) void init_kernel(
    const float* __restrict__ W1, const float* __restrict__ W2,
    unsigned short* __restrict__ img1, unsigned short* __restrict__ img2,
    int* __restrict__ cnt, float* __restrict__ part, int partN4, int N) {
  const int gtid = blockIdx.x * 256 + threadIdx.x;
  const int gsz = gridDim.x * 256;
  f32x4* p4 = (f32x4*)part;
  for (int i = gtid; i < partN4; i += gsz) p4[i] = f32x4{0.f, 0.f, 0.f, 0.f};
  for (int i = gtid; i < N; i += gsz) cnt[i] = 0;
  // img layout: element (k, n) at byte ((k>>3)*W + n)*16 + 2*(k&7)
  for (int i = gtid; i < 96 * 64 + 64 * 400; i += gsz) {
    if (i < 96 * 64) {
      const int m = i >> 6, n = i & 63;
      float v = 0.0f;
      if (m < 50) v = W1[m * 64 + n];                        // gaussian rows
      else if (m >= 56 && m < 88) v = W1[(m - 6) * 64 + n];  // ss, ds rows
      img1[((m >> 3) * 64 + n) * 8 + (m & 7)] = f2h(v);
    } else {
      const int j = i - 96 * 64;
      const int m = j / 400, n = j % 400;
      img2[((m >> 3) * 400 + n) * 8 + (m & 7)] = f2h(W2[m * 400 + n]);
    }
  }
}

// ---------- B: histogram of dst + per-edge rank (the ONLY atomic pass) -------
__global__ __launch_bounds__(256) void hist_rank_kernel(
    const int* __restrict__ edge_index, int* __restrict__ cnt,
    int* __restrict__ rank, int E) {
  const int e = blockIdx.x * blockDim.x + threadIdx.x;
  if (e >= E) return;
  rank[e] = atomicAdd(cnt + edge_index[E + e], 1);
}

// ---------- C: exclusive scan cnt -> node_start (single block, wave-scan) ----
__global__ __launch_bounds__(256) void scan_kernel(
    const int* __restrict__ cnt, int* __restrict__ node_start, int N) {
  __shared__ int wsum[4];
  const int tid = threadIdx.x;
  const int lane = tid & 63;
  const int wv = tid >> 6;
  const int n4 = (N + 3) >> 2;
  const int tiles = (n4 + 255) / 256;
  int running = 0;
  for (int k = 0; k < tiles; ++k) {
    const int i4 = k * 256 + tid;
    int4 v = {0, 0, 0, 0};
    const int base = i4 * 4;
    if (i4 < n4) {
      if (base + 3 < N) {
        v = *(const int4*)(cnt + base);
      } else {
        if (base + 0 < N) v.x = cnt[base + 0];
        if (base + 1 < N) v.y = cnt[base + 1];
        if (base + 2 < N) v.z = cnt[base + 2];
      }
    }
    const int e1 = v.x, e2 = v.x + v.y, e3 = e2 + v.z, s4 = e3 + v.w;
    int incl = s4;
#pragma unroll
    for (int d = 1; d < 64; d <<= 1) {
      const int y = __shfl_up(incl, d);
      if (lane >= d) incl += y;
    }
    if (lane == 63) wsum[wv] = incl;
    __syncthreads();
    int wbase = 0;
#pragma unroll
    for (int w = 0; w < 4; ++w) wbase += (w < wv) ? wsum[w] : 0;
    const int block_total = wsum[0] + wsum[1] + wsum[2] + wsum[3];
    const int tbase = running + wbase + (incl - s4);
    if (i4 < n4) {
      if (base + 0 < N) node_start[base + 0] = tbase;
      if (base + 1 < N) node_start[base + 1] = tbase + e1;
      if (base + 2 < N) node_start[base + 2] = tbase + e2;
      if (base + 3 < N) node_start[base + 3] = tbase + e3;
    }
    running += block_total;
    __syncthreads();  // wsum reused next tile
  }
}

// ---------- D: scatter (ATOMIC-FREE: slot = node_start[d] + rank[e]) ---------
__global__ __launch_bounds__(256) void scatter_kernel(
    const int* __restrict__ edge_index, const int* __restrict__ node_start,
    const int* __restrict__ rank, int2* __restrict__ sedge, int E) {
  const int e = blockIdx.x * blockDim.x + threadIdx.x;
  if (e >= E) return;
  const int s = edge_index[e];
  const int d = edge_index[E + e];
  sedge[node_start[d] + rank[e]] = int2{s, d};
}

// ---------- E: main MFMA edge kernel (r13 body; head-slot store tail) --------
// Per wave: 64 edges (4 groups of 16). All LDS traffic is wave-local.
// ub row (208B) timeline: ef(96 f16, chunks 0..11) -> h(chunks 0..7) +
// sh/v1 stash(chunks 8..11) -> o0 f32(chunks 0..4, after hf hoist) ->
// msg(28 f32, chunks 0..6). LDS 53248 B => 3 blocks/CU.
// Tail: segment heads STORE partials to unique slots (no atomics, r17):
//   non-lane0 head at sorted pos t => t == node_start[dst] => slot = dst
//   lane0 head (t % 64 == 0)       => slot = N + t/64
__global__ __launch_bounds__(256, 3) void tfn_mfma_kernel(
    const float* __restrict__ node_attr, const float* __restrict__ pos,
    const float* __restrict__ b1, const float* __restrict__ b2,
    const char* __restrict__ img1, const char* __restrict__ img2,
    const int2* __restrict__ sedge, float* __restrict__ part, int N, int E) {
  __shared__ __align__(16) char ub[256 * kRowB];   // 53248 B (3 blocks/CU)

  const int tid = threadIdx.x;
  const int t = blockIdx.x * 256 + tid;
  const int lane = tid & 63;
  const int wv = tid >> 6;
  const int lc = lane & 15, lq = lane >> 4;

  const bool valid = (t < E);
  int src = 0, dstv = -1;
  if (valid) {
    const int2 se = sedge[t];
    src = se.x;
    dstv = se.y;
  }
  const int dn = valid ? dstv : 0;

  // ---- geometry ----
  const float psx = pos[src * 3 + 0], psy = pos[src * 3 + 1], psz = pos[src * 3 + 2];
  const float pdx = pos[dn * 3 + 0], pdy = pos[dn * 3 + 1], pdz = pos[dn * 3 + 2];
  const float vx = pdx - psx, vy = pdy - psy, vz = pdz - psz;
  const float dist = sqrtf(vx * vx + vy * vy + vz * vz);
  const float rinv = 1.0f / fmaxf(dist, 1e-8f);
  const float sh0 = kSqrt3 * (vy * rinv);
  const float sh1 = kSqrt3 * (vz * rinv);
  const float sh2 = kSqrt3 * (vx * rinv);

  const float* nas = node_attr + (size_t)src * kAttr;
  const float* nad = node_attr + (size_t)dn * kAttr;
  const float4 sa = *(const float4*)(nas + 0);
  const float4 sb = *(const float4*)(nas + 4);
  const float4 sc4 = *(const float4*)(nas + 8);
  const float4 sd4 = *(const float4*)(nas + 12);
  const float4 va = *(const float4*)(nas + 16);
  const float4 vb = *(const float4*)(nas + 20);
  const float4 vc = *(const float4*)(nas + 24);
  const float4 da = *(const float4*)(nad + 0);
  const float4 db = *(const float4*)(nad + 4);
  const float4 dc4 = *(const float4*)(nad + 8);
  const float4 dd4 = *(const float4*)(nad + 12);

  char* myrow = ub + tid * kRowB;

  // ---- write ef row (96 f16): [gauss50 | 0x6 | ss16 | ds16 | 0x8] ----
  {
    const float base = dist + 1e-6f;
#pragma unroll
    for (int c = 0; c < 6; ++c) {
      unsigned p[4];
#pragma unroll
      for (int u = 0; u < 4; ++u) {
        const int k = c * 8 + u * 2;
        const float d0 = base - (float)k * kStep;
        const float d1 = base - (float)(k + 1) * kStep;
        p[u] = pack2(__expf(kCoeff * d0 * d0), __expf(kCoeff * d1 * d1));
      }
      *(u32x4*)(myrow + c * 16) = u32x4{p[0], p[1], p[2], p[3]};
    }
    const float d0 = base - 48.0f * kStep, d1 = base - 49.0f * kStep;
    *(u32x4*)(myrow + 6 * 16) =
        u32x4{pack2(__expf(kCoeff * d0 * d0), __expf(kCoeff * d1 * d1)), 0u, 0u, 0u};
    *(u32x4*)(myrow + 7 * 16) =
        u32x4{pack2(sa.x, sa.y), pack2(sa.z, sa.w), pack2(sb.x, sb.y), pack2(sb.z, sb.w)};
    *(u32x4*)(myrow + 8 * 16) =
        u32x4{pack2(sc4.x, sc4.y), pack2(sc4.z, sc4.w), pack2(sd4.x, sd4.y), pack2(sd4.z, sd4.w)};
    *(u32x4*)(myrow + 9 * 16) =
        u32x4{pack2(da.x, da.y), pack2(da.z, da.w), pack2(db.x, db.y), pack2(db.z, db.w)};
    *(u32x4*)(myrow + 10 * 16) =
        u32x4{pack2(dc4.x, dc4.y), pack2(dc4.z, dc4.w), pack2(dd4.x, dd4.y), pack2(dd4.z, dd4.w)};
    *(u32x4*)(myrow + 11 * 16) = u32x4{0u, 0u, 0u, 0u};
  }

  const float v1f[12] = {va.x, va.y, va.z, va.w, vb.x, vb.y, vb.z, vb.w,
                         vc.x, vc.y, vc.z, vc.w};

  // ---- hoist ef fragments (B-operand: lane holds ef[e=g*16+lc][k=(ks*4+lq)*8+j]) ----
  half8 eff[4][3];
#pragma unroll
  for (int g = 0; g < 4; ++g) {
    const char* rp = ub + (wv * 64 + g * 16 + lc) * kRowB;
#pragma unroll
    for (int ks = 0; ks < 3; ++ks)
      eff[g][ks] = *(const half8*)(rp + (ks * 4 + lq) * 16);
  }

  // ---- stash sh/v1 as f32 into chunks 8..11 (ef chunks 8..11 now dead) ----
  *(f32x4*)(myrow + 8 * 16) = f32x4{sh0, sh1, sh2, v1f[0]};
  *(f32x4*)(myrow + 9 * 16) = f32x4{v1f[1], v1f[2], v1f[3], v1f[4]};
  *(f32x4*)(myrow + 10 * 16) = f32x4{v1f[5], v1f[6], v1f[7], v1f[8]};
  *(f32x4*)(myrow + 11 * 16) = f32x4{v1f[9], v1f[10], v1f[11], 0.0f};

  // ---- MFMA-1: h[n][e] = relu(b1[n] + sum_k W1p[k][n] ef[e][k]) ----
#pragma unroll
  for (int nt = 0; nt < 4; ++nt) {
    const half8 a0 = *(const half8*)(img1 + ((0 + lq) * 64 + nt * 16 + lc) * 16);
    const half8 a1 = *(const half8*)(img1 + ((4 + lq) * 64 + nt * 16 + lc) * 16);
    const half8 a2 = *(const half8*)(img1 + ((8 + lq) * 64 + nt * 16 + lc) * 16);
    const f32x4 bias = *(const f32x4*)(b1 + nt * 16 + lq * 4);
#pragma unroll
    for (int g = 0; g < 4; ++g) {
      f32x4 acc = bias;
      acc = __builtin_amdgcn_mfma_f32_16x16x32_f16(a0, eff[g][0], acc, 0, 0, 0);
      acc = __builtin_amdgcn_mfma_f32_16x16x32_f16(a1, eff[g][1], acc, 0, 0, 0);
      acc = __builtin_amdgcn_mfma_f32_16x16x32_f16(a2, eff[g][2], acc, 0, 0, 0);
      const unsigned p0 = pack2(fmaxf(acc[0], 0.0f), fmaxf(acc[1], 0.0f));
      const unsigned p1 = pack2(fmaxf(acc[2], 0.0f), fmaxf(acc[3], 0.0f));
      const int row = wv * 64 + g * 16 + lc;
      // n = nt*16 + lq*4 + r -> byte 2n = nt*32 + lq*8
      *(u32x2*)(ub + row * kRowB + nt * 32 + lq * 8) = u32x2{p0, p1};
    }
  }

  // ---- load h fragments (B-operand: lane holds h[k][e=g*16+lc]) ----
  half8 hf[4][2];
#pragma unroll
  for (int g = 0; g < 4; ++g) {
    const char* rp = ub + (wv * 64 + g * 16 + lc) * kRowB;
    hf[g][0] = *(const half8*)(rp + (0 + lq) * 16);
    hf[g][1] = *(const half8*)(rp + (4 + lq) * 16);
  }

  // ---- hoist per-edge sh / v1 (lane owns edge lc of each group) ----
  float shv[4][3], v1h[4][3];
#pragma unroll
  for (int g = 0; g < 4; ++g) {
    const char* rp = ub + (wv * 64 + g * 16 + lc) * kRowB;
#pragma unroll
    for (int c = 0; c < 3; ++c) {
      shv[g][c] = *(const float*)(rp + 128 + 4 * c);
      v1h[g][c] = *(const float*)(rp + 140 + 12 * lq + 4 * c);
    }
  }

  // ---- o0[20] as f32 into chunks 0..4 (h region dead now that hf is in regs) ----
  {
    const float t0 = (v1f[0] * sh0 + v1f[1] * sh1 + v1f[2] * sh2) * kInvSqrt3;
    const float t1 = (v1f[3] * sh0 + v1f[4] * sh1 + v1f[5] * sh2) * kInvSqrt3;
    const float t2 = (v1f[6] * sh0 + v1f[7] * sh1 + v1f[8] * sh2) * kInvSqrt3;
    const float t3 = (v1f[9] * sh0 + v1f[10] * sh1 + v1f[11] * sh2) * kInvSqrt3;
    *(f32x4*)(myrow + 0) = f32x4{sa.x, sa.y, sa.z, sa.w};
    *(f32x4*)(myrow + 16) = f32x4{sb.x, sb.y, sb.z, sb.w};
    *(f32x4*)(myrow + 32) = f32x4{sc4.x, sc4.y, sc4.z, sc4.w};
    *(f32x4*)(myrow + 48) = f32x4{sd4.x, sd4.y, sd4.z, sd4.w};
    *(f32x4*)(myrow + 64) = f32x4{t0, t1, t2, t3};
  }

  // ---- MFMA-2 + fused contraction. D[n][e]: lane owns edge lc, n = 16nt+4lq+r ----
  float macc0[4][4] = {};
  float macc1[4][4][3] = {};

#pragma unroll 5
  for (int nt = 0; nt < 20; ++nt) {
    const half8 w0 = *(const half8*)(img2 + ((0 + lq) * 400 + nt * 16 + lc) * 16);
    const half8 w1 = *(const half8*)(img2 + ((4 + lq) * 400 + nt * 16 + lc) * 16);
    const f32x4 bias = *(const f32x4*)(b2 + nt * 16 + lq * 4);
#pragma unroll
    for (int g = 0; g < 4; ++g) {
      f32x4 acc = bias;
      acc = __builtin_amdgcn_mfma_f32_16x16x32_f16(w0, hf[g][0], acc, 0, 0, 0);
      acc = __builtin_amdgcn_mfma_f32_16x16x32_f16(w1, hf[g][1], acc, 0, 0, 0);
      const char* rp0 = ub + (wv * 64 + g * 16 + lc) * kRowB;
      const float o0v = *(const float*)(rp0 + 4 * nt);   // broadcast (4 lanes/addr)
#pragma unroll
      for (int r = 0; r < 4; ++r) macc0[g][r] = fmaf(o0v, acc[r], macc0[g][r]);
    }
  }
#pragma unroll
  for (int nt = 20; nt < 24; ++nt) {
    const half8 w0 = *(const half8*)(img2 + ((0 + lq) * 400 + nt * 16 + lc) * 16);
    const half8 w1 = *(const half8*)(img2 + ((4 + lq) * 400 + nt * 16 + lc) * 16);
    const f32x4 bias = *(const f32x4*)(b2 + nt * 16 + lq * 4);
#pragma unroll
    for (int g = 0; g < 4; ++g) {
      f32x4 acc = bias;
      acc = __builtin_amdgcn_mfma_f32_16x16x32_f16(w0, hf[g][0], acc, 0, 0, 0);
      acc = __builtin_amdgcn_mfma_f32_16x16x32_f16(w1, hf[g][1], acc, 0, 0, 0);
      const char* rp0 = ub + (wv * 64 + g * 16 + lc) * kRowB;
      // i = 4*(nt-20) + lq, o = r; o1[i] = ss[i] * sh; ss[i] = o0[i] (f32)
      const float ssv = *(const float*)(rp0 + 16 * (nt - 20) + 4 * lq);
      float pc[3];
#pragma unroll
      for (int c = 0; c < 3; ++c) pc[c] = ssv * shv[g][c];
#pragma unroll
      for (int r = 0; r < 4; ++r)
#pragma unroll
        for (int c = 0; c < 3; ++c)
          macc1[g][r][c] = fmaf(pc[c], acc[r], macc1[g][r][c]);
    }
  }
  {  // nt = 24: i = 16 + lq, o1 row = in_1o
    const int nt = 24;
    const half8 w0 = *(const half8*)(img2 + ((0 + lq) * 400 + nt * 16 + lc) * 16);
    const half8 w1 = *(const half8*)(img2 + ((4 + lq) * 400 + nt * 16 + lc) * 16);
    const f32x4 bias = *(const f32x4*)(b2 + nt * 16 + lq * 4);
#pragma unroll
    for (int g = 0; g < 4; ++g) {
      f32x4 acc = bias;
      acc = __builtin_amdgcn_mfma_f32_16x16x32_f16(w0, hf[g][0], acc, 0, 0, 0);
      acc = __builtin_amdgcn_mfma_f32_16x16x32_f16(w1, hf[g][1], acc, 0, 0, 0);
#pragma unroll
      for (int r = 0; r < 4; ++r)
#pragma unroll
        for (int c = 0; c < 3; ++c)
          macc1[g][r][c] = fmaf(v1h[g][c], acc[r], macc1[g][r][c]);
    }
  }

  // ---- finish msg1 (reduce i-partition across lq groups), scale, write msg rows ----
#pragma unroll
  for (int g = 0; g < 4; ++g)
#pragma unroll
    for (int r = 0; r < 4; ++r)
#pragma unroll
      for (int c = 0; c < 3; ++c) {
        float x = macc1[g][r][c];
        x += __shfl_xor(x, 16);
        x += __shfl_xor(x, 32);
        macc1[g][r][c] = x * kInvSqrt20;
      }
#pragma unroll
  for (int g = 0; g < 4; ++g) {
    char* rp = ub + (wv * 64 + g * 16 + lc) * kRowB;
    *(f32x4*)(rp + lq * 16) =
        f32x4{macc0[g][0] * kInvSqrt20, macc0[g][1] * kInvSqrt20,
              macc0[g][2] * kInvSqrt20, macc0[g][3] * kInvSqrt20};
    f32x4 m1;
    if (lq == 1)
      m1 = f32x4{macc1[g][0][0], macc1[g][0][1], macc1[g][0][2], macc1[g][1][0]};
    else if (lq == 2)
      m1 = f32x4{macc1[g][1][1], macc1[g][1][2], macc1[g][2][0], macc1[g][2][1]};
    else
      m1 = f32x4{macc1[g][2][2], macc1[g][3][0], macc1[g][3][1], macc1[g][3][2]};
    if (lq != 0) *(f32x4*)(rp + 48 + lq * 16) = m1;
  }

  // ---- read back own msg, segmented wave reduction, head-slot STORES ----
  float msg[28];
  {
    const char* rp = ub + tid * kRowB;
#pragma unroll
    for (int c = 0; c < 7; ++c) {
      const f32x4 v = *(const f32x4*)(rp + c * 16);
      msg[c * 4 + 0] = v[0];
      msg[c * 4 + 1] = v[1];
      msg[c * 4 + 2] = v[2];
      msg[c * 4 + 3] = v[3];
    }
  }
#pragma unroll
  for (int d = 1; d < 64; d <<= 1) {
    const int od = __shfl_down(dstv, d);
    const bool same = (lane + d < 64) && (od == dstv);
#pragma unroll
    for (int j = 0; j < 28; j++) {
      const float ov = __shfl_down(msg[j], d);
      if (same) msg[j] += ov;
    }
  }
  const int pd = __shfl_up(dstv, 1);
  if ((lane == 0 || pd != dstv) && dstv >= 0) {
    // unique head slot: lane0 head -> N + t/64 (t % 64 == 0); other heads are
    // first-of-node (t == node_start[dst]) -> slot dst. Plain stores, no RMW.
    const int slot = (lane == 0) ? (N + (t >> 6)) : dstv;
    float* pp = part + (size_t)slot * kAttr;
#pragma unroll
    for (int c = 0; c < 7; ++c)
      *(f32x4*)(pp + c * 4) =
          f32x4{msg[c * 4 + 0], msg[c * 4 + 1], msg[c * 4 + 2], msg[c * 4 + 3]};
  }
}

// ---------- F: finalize — sum 1-2 head slots, normalize, add node_attr ------
__global__ __launch_bounds__(256) void tfn_finalize_kernel(
    const float* __restrict__ node_attr, const int* __restrict__ cnt,
    const int* __restrict__ node_start, const float* __restrict__ part,
    float* __restrict__ out, int N, int total) {
  const int i = blockIdx.x * blockDim.x + threadIdx.x;
  if (i >= total) return;
  const int n = i / kAttr;
  const int j = i - n * kAttr;
  const int c = cnt[n];
  float s = part[(size_t)n * kAttr + j];          // first-of-node slot (0 if unused)
  const int ns = node_start[n];
  // wave-boundary heads: multiples of 64 in [ns, ns+c)
  for (int k = (ns + 63) >> 6; k * 64 < ns + c; ++k)
    s += part[(size_t)(N + k) * kAttr + j];
  out[i] = node_attr[i] + s / fmaxf((float)c, 1.0f);
}

extern "C" void kernel_launch(void* const* d_in, const int* in_sizes, int n_in,
                              void* d_out, int out_size, void* d_ws, size_t ws_size,
                              hipStream_t stream) {
  const float* node_attr = (const float*)d_in[0];
  const float* pos = (const float*)d_in[1];
  const float* W1 = (const float*)d_in[2];
  const float* b1 = (const float*)d_in[3];
  const float* W2 = (const float*)d_in[4];
  const float* b2 = (const float*)d_in[5];
  const int* edge_index = (const int*)d_in[6];

  const int N = in_sizes[0] / kAttr;
  const int E = in_sizes[6] / 2;
  const int nslots = N + (E + 63) / 64;

  // ws layout: [img1][img2][cnt N][node_start N][rank E][sedge E int2]
  //            [part nslots*28 f32]  ~5.7MB total (ws proven >= 7.8MB, r7)
  char* wsc = (char*)d_ws;
  unsigned short* img1 = (unsigned short*)wsc;
  unsigned short* img2 = (unsigned short*)(wsc + kImg1Bytes);
  int* cnt = (int*)(wsc + kImg1Bytes + kImg2Bytes);
  int* node_start = cnt + N;
  int* rank = node_start + N;
  int2* sedge = (int2*)(rank + E);
  float* part = (float*)(sedge + E);

  const int partN4 = (nslots * kAttr) / 4;  // 28 % 4 == 0
  const int eblocks = (E + 255) / 256;
  const int total = N * kAttr;

  // 6 dispatches, all plain (r9: no grid.sync; r8: no mega-fuse; r13: one
  // atomic pass; r17: main kernel fully atomic-free via head slots).
  init_kernel<<<512, 256, 0, stream>>>(W1, W2, img1, img2, cnt, part, partN4, N);
  hist_rank_kernel<<<eblocks, 256, 0, stream>>>(edge_index, cnt, rank, E);
  scan_kernel<<<1, 256, 0, stream>>>(cnt, node_start, N);
  scatter_kernel<<<eblocks, 256, 0, stream>>>(edge_index, node_start, rank,
                                              sedge, E);
  tfn_mfma_kernel<<<eblocks, 256, 0, stream>>>(
      node_attr, pos, b1, b2, (const char*)img1, (const char*)img2,
      sedge, part, N, E);
  tfn_finalize_kernel<<<(total + 255) / 256, 256, 0, stream>>>(
      node_attr, cnt, node_start, part, (float*)d_out, N, total);
}